// Round 16
// baseline (249.111 us; speedup 1.0000x reference)
//
#include <hip/hip_runtime.h>
#include <hip/hip_bf16.h>

// Problem constants
#define BATCH 4
#define CDIM 256
#define HWSZ 4096          // 64*64
#define P2 1024            // 32*32 pooled pixels per batch
#define SCALE 0.17677669529663687f
#define LOG2E 1.4426950408889634f
#define SCL2 (SCALE * LOG2E)
#define EPS_GN 1e-6f
#define EPS_LN 1e-5f
#define MFIX 8.0f          // fixed softmax shift (scores are O(1); exp(s-8) can't overflow)
#define MFIX2 (MFIX * LOG2E)

typedef short v8s __attribute__((ext_vector_type(8)));
typedef float v4f __attribute__((ext_vector_type(4)));

__device__ __forceinline__ unsigned short f2bf(float f) {
    __hip_bfloat16 h = __float2bfloat16(f);
    return *reinterpret_cast<unsigned short*>(&h);
}
__device__ __forceinline__ float bf2f(unsigned short u) {
    return __uint_as_float(((unsigned int)u) << 16);
}
__device__ __forceinline__ float bflo(unsigned int u) {
    return __uint_as_float(u << 16);
}
__device__ __forceinline__ float bfhi(unsigned int u) {
    return __uint_as_float(u & 0xffff0000u);
}
__device__ __forceinline__ unsigned int pack2(float lo, float hi) {
    return (unsigned int)f2bf(lo) | ((unsigned int)f2bf(hi) << 16);
}
// truncating bf16 pack (P-values only: softmax ratio cancels the truncation bias)
__device__ __forceinline__ unsigned int tpack2(float lo, float hi) {
    return (__float_as_uint(lo) >> 16) | (__float_as_uint(hi) & 0xffff0000u);
}
__device__ __forceinline__ float fexp2(float x) {
#if __has_builtin(__builtin_amdgcn_exp2f)
    return __builtin_amdgcn_exp2f(x);
#else
    return exp2f(x);
#endif
}
// 2^(s-MFIX2) for 4 log2-domain scores -> packed 4xbf16 (truncated), accumulating sum
__device__ __forceinline__ uint2 expack2(v4f s, float& sum) {
    float a = fexp2(s[0] - MFIX2);
    float b = fexp2(s[1] - MFIX2);
    float c = fexp2(s[2] - MFIX2);
    float d = fexp2(s[3] - MFIX2);
    sum += (a + b) + (c + d);
    return make_uint2(tpack2(a, b), tpack2(c, d));
}
__device__ __forceinline__ v8s u4v8(uint2 a, uint2 b) {
    union { unsigned int u[4]; v8s v; } r;
    r.u[0] = a.x; r.u[1] = a.y; r.u[2] = b.x; r.u[3] = b.y;
    return r.v;
}
// V key permutation within a 64-key block: S^T reg order -> PV A-frag contract order.
__device__ __forceinline__ int vperm(int j) {
    return (j & 0x23) | ((j & 0x0C) << 1) | ((j & 0x10) >> 2);
}
__device__ __forceinline__ void async16(void* lds, const void* g) {
    __builtin_amdgcn_global_load_lds(
        (const __attribute__((address_space(1))) unsigned int*)g,
        (__attribute__((address_space(3))) unsigned int*)lds, 16, 0, 0);
}

// ------- prep: weight cast (blocks 0..703) + GN partial stats of x (blocks 704..959) ----
__global__ void prep_kernel(const float* __restrict__ w0, const float* __restrict__ w1,
                            const float* __restrict__ w2, const float* __restrict__ w3,
                            const float* __restrict__ w4, unsigned short* __restrict__ dst,
                            const float* __restrict__ x, float* __restrict__ part)
{
    int bid = blockIdx.x;
    int tid = threadIdx.x;
    if (bid < 704) {
        int idx = (bid * 256 + tid) * 4;
        const float* src; int off;
        if      (idx < 196608) { src = w0; off = 0; }
        else if (idx < 458752) { src = w1; off = 196608; }
        else if (idx < 589824) { src = w2; off = 458752; }
        else if (idx < 655360) { src = w3; off = 589824; }
        else                   { src = w4; off = 655360; }
        float4 v = *(const float4*)(src + idx - off);
        *(uint2*)(dst + idx) = make_uint2(pack2(v.x, v.y), pack2(v.z, v.w));
        return;
    }
    // x stats: 256 blocks, nblk=64 per batch, pb4=262144
    int blk2 = bid - 704;
    int bb = blk2 >> 6, blk = blk2 & 63;
    const float* pa = x + (size_t)bb * 1048576;
    float s = 0.f, s2 = 0.f;
    for (int i = blk * 256 + tid; i < 262144; i += 64 * 256) {
        float4 v = *(const float4*)(pa + (size_t)i * 4);
        s += (v.x + v.y) + (v.z + v.w);
        s2 += fmaf(v.x, v.x, fmaf(v.y, v.y, fmaf(v.z, v.z, v.w * v.w)));
    }
    __shared__ float ls[256], ls2[256];
    ls[tid] = s; ls2[tid] = s2; __syncthreads();
    for (int off = 128; off > 0; off >>= 1) {
        if (tid < off) { ls[tid] += ls[tid + off]; ls2[tid] += ls2[tid + off]; }
        __syncthreads();
    }
    if (tid == 0) {
        part[blk2 * 2]     = ls[0];
        part[blk2 * 2 + 1] = ls2[0];
    }
}

// ---------------- GroupNorm partial stats (fp32 a + optional bf16 addend) ----------
__global__ void gn_partial4(const float* __restrict__ a, const unsigned short* __restrict__ a2bf,
                            int pb4, int nblk, float* __restrict__ part)
{
    int bb  = blockIdx.x / nblk;
    int blk = blockIdx.x % nblk;
    const float* pa = a + (size_t)bb * pb4 * 4;
    const unsigned short* pa2 = a2bf ? a2bf + (size_t)bb * pb4 * 4 : nullptr;
    int tid = threadIdx.x;
    float s = 0.f, s2 = 0.f;
    for (int i = blk * 256 + tid; i < pb4; i += nblk * 256) {
        float4 v = *(const float4*)(pa + (size_t)i * 4);
        if (pa2) {
            uint2 g = *(const uint2*)(pa2 + (size_t)i * 4);
            v.x += bflo(g.x); v.y += bfhi(g.x);
            v.z += bflo(g.y); v.w += bfhi(g.y);
        }
        s += (v.x + v.y) + (v.z + v.w);
        s2 += fmaf(v.x, v.x, fmaf(v.y, v.y, fmaf(v.z, v.z, v.w * v.w)));
    }
    __shared__ float ls[256], ls2[256];
    ls[tid] = s; ls2[tid] = s2; __syncthreads();
    for (int off = 128; off > 0; off >>= 1) {
        if (tid < off) { ls[tid] += ls[tid + off]; ls2[tid] += ls2[tid + off]; }
        __syncthreads();
    }
    if (tid == 0) {
        part[blockIdx.x * 2]     = ls[0];
        part[blockIdx.x * 2 + 1] = ls2[0];
    }
}

// ------- transpose + (optional bf16 add) + norm (stats finalized inline) + cast ---------
// A: [b][256][P] fp32 c-major.  A2b: optional bf16 addend same layout.  dst: [b][P][256] bf16.
__global__ __launch_bounds__(256) void tnc(
    const float* __restrict__ A, const unsigned short* __restrict__ A2b,
    const float* __restrict__ part, int nblk, float inv_n, float eps,
    const float* __restrict__ nw, const float* __restrict__ nb,
    unsigned short* __restrict__ dst, int P)
{
    int b = blockIdx.z, c0 = blockIdx.y * 64, p0 = blockIdx.x * 64;
    __shared__ float ld[64][65];
    __shared__ float sstat[2];
    int t = threadIdx.x;
    if (t < 64) {
        float s = 0.f, s2 = 0.f;
        if (t < nblk) {
            s  = part[(b * nblk + t) * 2];
            s2 = part[(b * nblk + t) * 2 + 1];
        }
        #pragma unroll
        for (int off = 32; off > 0; off >>= 1) {
            s  += __shfl_down(s, off);
            s2 += __shfl_down(s2, off);
        }
        if (t == 0) {
            float mval = s * inv_n;
            float var  = s2 * inv_n - mval * mval;
            sstat[0] = mval;
            sstat[1] = rsqrtf(var + eps);
        }
    }
    __syncthreads();
    float mean = sstat[0], rstd = sstat[1];
    {
        int ch = t >> 2, pq = (t & 3) * 16;
        size_t base = ((size_t)b * 256 + c0 + ch) * P + p0 + pq;
        float4 f0 = *(const float4*)(A + base);
        float4 f1 = *(const float4*)(A + base + 4);
        float4 f2 = *(const float4*)(A + base + 8);
        float4 f3 = *(const float4*)(A + base + 12);
        if (A2b) {
            const unsigned short* ap = A2b + base;
            uint4 q0 = *(const uint4*)(ap);
            uint4 q1 = *(const uint4*)(ap + 8);
            f0.x += bflo(q0.x); f0.y += bfhi(q0.x); f0.z += bflo(q0.y); f0.w += bfhi(q0.y);
            f1.x += bflo(q0.z); f1.y += bfhi(q0.z); f1.z += bflo(q0.w); f1.w += bfhi(q0.w);
            f2.x += bflo(q1.x); f2.y += bfhi(q1.x); f2.z += bflo(q1.y); f2.w += bfhi(q1.y);
            f3.x += bflo(q1.z); f3.y += bfhi(q1.z); f3.z += bflo(q1.w); f3.w += bfhi(q1.w);
        }
        float wv = nw[c0 + ch];
        float sw = rstd * wv;
        float sb = nb[c0 + ch] - mean * rstd * wv;
        ld[ch][pq + 0]  = f0.x * sw + sb; ld[ch][pq + 1]  = f0.y * sw + sb;
        ld[ch][pq + 2]  = f0.z * sw + sb; ld[ch][pq + 3]  = f0.w * sw + sb;
        ld[ch][pq + 4]  = f1.x * sw + sb; ld[ch][pq + 5]  = f1.y * sw + sb;
        ld[ch][pq + 6]  = f1.z * sw + sb; ld[ch][pq + 7]  = f1.w * sw + sb;
        ld[ch][pq + 8]  = f2.x * sw + sb; ld[ch][pq + 9]  = f2.y * sw + sb;
        ld[ch][pq + 10] = f2.z * sw + sb; ld[ch][pq + 11] = f2.w * sw + sb;
        ld[ch][pq + 12] = f3.x * sw + sb; ld[ch][pq + 13] = f3.y * sw + sb;
        ld[ch][pq + 14] = f3.z * sw + sb; ld[ch][pq + 15] = f3.w * sw + sb;
    }
    __syncthreads();
    {
        int p = t >> 2, cb = (t & 3) * 16;
        unsigned int u[8];
        #pragma unroll
        for (int j = 0; j < 8; j++)
            u[j] = pack2(ld[cb + 2 * j][p], ld[cb + 2 * j + 1][p]);
        unsigned short* dp = dst + ((size_t)b * P + p0 + p) * 256 + c0 + cb;
        *(uint4*)(dp)     = make_uint4(u[0], u[1], u[2], u[3]);
        *(uint4*)(dp + 8) = make_uint4(u[4], u[5], u[6], u[7]);
    }
}

// ---------------- MFMA GEMM (128x128 tile): OUT = actT * W^T + bias ----------
// MODE 0: OUT fp32 c-major [B][OC][P]; optional partOut: per-block (sum,sumsq) partials.
// MODE 1: qkv split -> aux1 = qkp bf16 [B][4096][512] p-major (ch<512);
//         ch>=512 (V) -> aux2 bf16 c-major [B][256][4096].
// MODE 2: head-split p-major bf16 [B*8][P][32], (acc+bias)*oscale  (Q path).
// MODE 3: kv: ch<256 (K) -> aux1 [B*8][1024][32] p-major; ch>=256 (V) -> aux2 [B*8][32][1024]
//         c-major with vperm'd key positions.
template<int MODE>
__global__ __launch_bounds__(256, 3) void gemm_bf16(
    const unsigned short* __restrict__ actT,
    const unsigned short* __restrict__ Wb,
    const float* __restrict__ bias,
    float* __restrict__ out,
    unsigned short* __restrict__ aux1,
    unsigned short* __restrict__ aux2,
    float* __restrict__ partOut,
    int K, int P, int OC, float oscale)
{
    int b  = blockIdx.z;
    int p0 = blockIdx.x * 128;
    int m0 = blockIdx.y * 128;
    int tid = threadIdx.x;
    int w = tid >> 6, lane = tid & 63;
    int lm = lane & 15, lg = lane >> 4;
    int wm = w >> 1, wp = w & 1;
    int l8 = lane >> 3, cc = lane & 7;

    __shared__ __align__(16) unsigned short Wt[128 * 64];   // [m][64k], swizzled
    __shared__ __align__(16) unsigned short At[128 * 64];   // [p][64k], swizzled

    const unsigned short* actB = actT + (size_t)b * P * K;

    v4f acc[4][4];
    #pragma unroll
    for (int i = 0; i < 4; i++)
        #pragma unroll
        for (int j = 0; j < 4; j++) acc[i][j] = (v4f){0.f, 0.f, 0.f, 0.f};

    for (int ks = 0; ks < K; ks += 64) {
        #pragma unroll
        for (int i = 0; i < 4; i++) {
            int ml = w * 32 + i * 8 + l8;
            int g = cc ^ (ml & 7);
            async16(&Wt[ml * 64], Wb + (size_t)(m0 + ml) * K + ks + g * 8);
        }
        #pragma unroll
        for (int i = 0; i < 4; i++) {
            int pl = w * 32 + i * 8 + l8;
            int g = cc ^ (pl & 7);
            async16(&At[pl * 64], actB + (size_t)(p0 + pl) * K + ks + g * 8);
        }
        __syncthreads();
        #pragma unroll
        for (int kk = 0; kk < 2; kk++) {
            v8s af[4], bfv[4];
            #pragma unroll
            for (int mt = 0; mt < 4; mt++) {
                int m = wm * 64 + mt * 16 + lm;
                int ch = (kk * 4 + lg) ^ (m & 7);
                af[mt] = *(const v8s*)&Wt[m * 64 + ch * 8];
            }
            #pragma unroll
            for (int pt = 0; pt < 4; pt++) {
                int p = wp * 64 + pt * 16 + lm;
                int ch = (kk * 4 + lg) ^ (p & 7);
                bfv[pt] = *(const v8s*)&At[p * 64 + ch * 8];
            }
            #pragma unroll
            for (int mt = 0; mt < 4; mt++)
                #pragma unroll
                for (int pt = 0; pt < 4; pt++)
                    acc[mt][pt] = __builtin_amdgcn_mfma_f32_16x16x32_bf16(
                        af[mt], bfv[pt], acc[mt][pt], 0, 0, 0);
        }
        __syncthreads();
    }

    if constexpr (MODE == 1) {
        if (m0 < 512) {
            #pragma unroll
            for (int mt = 0; mt < 4; mt++) {
                int mch = m0 + wm * 64 + mt * 16 + lg * 4;
                float4 bs = *(const float4*)(bias + mch);
                #pragma unroll
                for (int pt = 0; pt < 4; pt++) {
                    int p = p0 + wp * 64 + pt * 16 + lm;
                    unsigned int u0 = pack2(acc[mt][pt][0] + bs.x, acc[mt][pt][1] + bs.y);
                    unsigned int u1 = pack2(acc[mt][pt][2] + bs.z, acc[mt][pt][3] + bs.w);
                    *(uint2*)(aux1 + ((size_t)(b * 4096 + p) * 512 + mch)) = make_uint2(u0, u1);
                }
            }
        } else {
            // V -> bf16 c-major [b][256][4096]
            #pragma unroll
            for (int mt = 0; mt < 4; mt++) {
                #pragma unroll
                for (int r = 0; r < 4; r++) {
                    int mch = m0 + wm * 64 + mt * 16 + lg * 4 + r;
                    float bsv = bias[mch];
                    unsigned short* orow = aux2 + ((size_t)b * 256 + (mch - 512)) * 4096
                                           + p0 + wp * 64;
                    #pragma unroll
                    for (int pt = 0; pt < 4; pt++)
                        orow[pt * 16 + lm] = f2bf(acc[mt][pt][r] + bsv);
                }
            }
        }
    } else if constexpr (MODE == 2) {
        #pragma unroll
        for (int mt = 0; mt < 4; mt++) {
            int ch = m0 + wm * 64 + mt * 16 + lg * 4;
            int head = ch >> 5, d = ch & 31;
            float4 bs = *(const float4*)(bias + ch);
            #pragma unroll
            for (int pt = 0; pt < 4; pt++) {
                int p = p0 + wp * 64 + pt * 16 + lm;
                unsigned int u0 = pack2((acc[mt][pt][0] + bs.x) * oscale,
                                        (acc[mt][pt][1] + bs.y) * oscale);
                unsigned int u1 = pack2((acc[mt][pt][2] + bs.z) * oscale,
                                        (acc[mt][pt][3] + bs.w) * oscale);
                *(uint2*)(aux1 + ((size_t)(b * 8 + head) * P + p) * 32 + d) = make_uint2(u0, u1);
            }
        }
    } else if constexpr (MODE == 3) {
        #pragma unroll
        for (int mt = 0; mt < 4; mt++) {
            int ch = m0 + wm * 64 + mt * 16 + lg * 4;
            if (ch < 256) {     // K -> p-major [bh][1024][32]
                int head = ch >> 5, d = ch & 31;
                float4 bs = *(const float4*)(bias + ch);
                #pragma unroll
                for (int pt = 0; pt < 4; pt++) {
                    int p = p0 + wp * 64 + pt * 16 + lm;
                    unsigned int u0 = pack2(acc[mt][pt][0] + bs.x, acc[mt][pt][1] + bs.y);
                    unsigned int u1 = pack2(acc[mt][pt][2] + bs.z, acc[mt][pt][3] + bs.w);
                    *(uint2*)(aux1 + ((size_t)(b * 8 + head) * P + p) * 32 + d) = make_uint2(u0, u1);
                }
            } else {            // V -> c-major [bh][32][1024], vperm'd positions
                int v = ch - 256;
                int head = v >> 5, d0 = v & 31;
                #pragma unroll
                for (int pt = 0; pt < 4; pt++) {
                    int p = p0 + wp * 64 + pt * 16 + lm;
                    int pos = (p & ~63) | vperm(p & 63);
                    #pragma unroll
                    for (int r = 0; r < 4; r++)
                        aux2[((size_t)(b * 8 + head) * 32 + d0 + r) * P + pos] =
                            f2bf(acc[mt][pt][r] + bias[ch + r]);
                }
            }
        }
    } else {
        float s = 0.f, s2 = 0.f;
        #pragma unroll
        for (int mt = 0; mt < 4; mt++) {
            #pragma unroll
            for (int r = 0; r < 4; r++) {
                int m = m0 + wm * 64 + mt * 16 + lg * 4 + r;
                float bs = bias ? bias[m] : 0.f;
                float* orow = out + (size_t)b * OC * P + (size_t)m * P + p0 + wp * 64;
                #pragma unroll
                for (int pt = 0; pt < 4; pt++) {
                    float v = acc[mt][pt][r] + bs;
                    orow[pt * 16 + lm] = v;
                    s += v; s2 = fmaf(v, v, s2);
                }
            }
        }
        if (partOut) {
            __shared__ float rs[256], rs2[256];
            rs[tid] = s; rs2[tid] = s2; __syncthreads();
            for (int off = 128; off > 0; off >>= 1) {
                if (tid < off) { rs[tid] += rs[tid + off]; rs2[tid] += rs2[tid + off]; }
                __syncthreads();
            }
            if (tid == 0) {
                int tilesPB = gridDim.x * gridDim.y;
                int tile = blockIdx.y * gridDim.x + blockIdx.x;
                partOut[((size_t)b * tilesPB + tile) * 2]     = rs[0];
                partOut[((size_t)b * tilesPB + tile) * 2 + 1] = rs2[0];
            }
        }
    }
}

// ---------------- local windowed attention, bf16 MFMA, fixed-max, LDS-free ----------------
// qkp: [B][4096][512] bf16 (Q ch 0-255, K ch 256-511); vbb: [B][256][4096] bf16 c-major.
// gxb: [B][256][4096] bf16 c-major output.
__global__ __launch_bounds__(256, 4) void local_attn_mfma(
    const unsigned short* __restrict__ qkp,
    const unsigned short* __restrict__ vbb,
    unsigned short* __restrict__ gxb)
{
    int win = blockIdx.x;                  // b*512 + h*64 + gy*8 + gxc
    int gxc = win & 7, gy = (win >> 3) & 7, h = (win >> 6) & 7, b = win >> 9;
    int w = threadIdx.x >> 6, lane = threadIdx.x & 63;
    int m = lane & 15, g = lane >> 4;

    int rowbase = (gy * 8) * 64 + gxc * 8;   // pixel of window token 0
    const unsigned short* qkb = qkp + (size_t)b * 4096 * 512;
    const unsigned short* vbase = vbb + (size_t)b * 256 * 4096;

    int tq = w * 16 + m;
    int pq = rowbase + (tq >> 3) * 64 + (tq & 7);
    v8s qf = *(const v8s*)(qkb + (size_t)pq * 512 + h * 32 + g * 8);

    v8s ka[4];
    #pragma unroll
    for (int kt = 0; kt < 4; kt++) {
        int tk = kt * 16 + m;
        int pk = rowbase + (tk >> 3) * 64 + (tk & 7);
        ka[kt] = *(const v8s*)(qkb + (size_t)pk * 512 + 256 + h * 32 + g * 8);
    }
    v8s vb[2][2];
    #pragma unroll
    for (int c = 0; c < 2; c++)
        #pragma unroll
        for (int dt = 0; dt < 2; dt++) {
            const unsigned short* vp = vbase + (size_t)(h * 32 + dt * 16 + m) * 4096
                              + rowbase + (4 * c + (g >> 1)) * 64 + (g & 1) * 4;
            vb[c][dt] = u4v8(*(const uint2*)vp, *(const uint2*)(vp + 128));
        }

    const v4f zf = {0.f, 0.f, 0.f, 0.f};
    v4f s[4];
    #pragma unroll
    for (int kt = 0; kt < 4; kt++)
        s[kt] = __builtin_amdgcn_mfma_f32_16x16x32_bf16(ka[kt], qf, zf, 0, 0, 0);

    float lsum = 0.f;
    uint2 u0, u1, u2, u3;
    {
        v4f sc;
        #pragma unroll
        for (int r = 0; r < 4; r++) sc[r] = s[0][r] * SCL2;
        u0 = expack2(sc, lsum);
        #pragma unroll
        for (int r = 0; r < 4; r++) sc[r] = s[1][r] * SCL2;
        u1 = expack2(sc, lsum);
        #pragma unroll
        for (int r = 0; r < 4; r++) sc[r] = s[2][r] * SCL2;
        u2 = expack2(sc, lsum);
        #pragma unroll
        for (int r = 0; r < 4; r++) sc[r] = s[3][r] * SCL2;
        u3 = expack2(sc, lsum);
    }
    lsum += __shfl_xor(lsum, 16);
    lsum += __shfl_xor(lsum, 32);
    float inv = 1.f / lsum;

    v8s pa0 = u4v8(u0, u1), pa1 = u4v8(u2, u3);
    v4f o0 = zf, o1 = zf;
    o0 = __builtin_amdgcn_mfma_f32_16x16x32_bf16(pa0, vb[0][0], o0, 0, 0, 0);
    o1 = __builtin_amdgcn_mfma_f32_16x16x32_bf16(pa0, vb[0][1], o1, 0, 0, 0);
    o0 = __builtin_amdgcn_mfma_f32_16x16x32_bf16(pa1, vb[1][0], o0, 0, 0, 0);
    o1 = __builtin_amdgcn_mfma_f32_16x16x32_bf16(pa1, vb[1][1], o1, 0, 0, 0);

    float invq[4];
    #pragma unroll
    for (int r = 0; r < 4; r++) invq[r] = __shfl(inv, g * 4 + r);

    int t0 = w * 16 + g * 4;
    int px0 = rowbase + (t0 >> 3) * 64 + (t0 & 7);
    unsigned short* op0 = gxb + ((size_t)b * 256 + h * 32 + m) * 4096 + px0;
    *(uint2*)op0 = make_uint2(pack2(o0[0] * invq[0], o0[1] * invq[1]),
                              pack2(o0[2] * invq[2], o0[3] * invq[3]));
    unsigned short* op1 = gxb + ((size_t)b * 256 + h * 32 + 16 + m) * 4096 + px0;
    *(uint2*)op1 = make_uint2(pack2(o1[0] * invq[0], o1[1] * invq[1]),
                              pack2(o1[2] * invq[2], o1[3] * invq[3]));
}

// ---------------- patch-merge layernorm (reads coalesced gxT, writes bf16 mn) ----------
__global__ __launch_bounds__(256) void patch_merge_ln2(
    const unsigned short* __restrict__ gxT,
    const float* __restrict__ lnw, const float* __restrict__ lnb,
    unsigned short* __restrict__ mn)
{
    int pix = blockIdx.x;
    int b = pix >> 10, op = pix & 1023;
    int oh = op >> 5, ow = op & 31;
    int t = threadIdx.x;
    const unsigned short* base = gxT + (size_t)b * 4096 * 256;
    float v[4];
    #pragma unroll
    for (int i = 0; i < 4; i++) {
        int h = 2 * oh + (i & 1);
        int w = 2 * ow + (i >> 1);
        v[i] = bf2f(base[(size_t)(h * 64 + w) * 256 + t]);
    }
    float s  = v[0] + v[1] + v[2] + v[3];
    float s2 = v[0]*v[0] + v[1]*v[1] + v[2]*v[2] + v[3]*v[3];
    __shared__ float ls[256], ls2[256];
    ls[t] = s; ls2[t] = s2; __syncthreads();
    for (int off = 128; off > 0; off >>= 1) {
        if (t < off) { ls[t] += ls[t + off]; ls2[t] += ls2[t + off]; }
        __syncthreads();
    }
    float mu  = ls[0] * (1.f / 1024.f);
    float var = ls2[0] * (1.f / 1024.f) - mu * mu;
    float r = rsqrtf(var + EPS_LN);
    unsigned short* orow = mn + (size_t)pix * 1024;
    #pragma unroll
    for (int i = 0; i < 4; i++) {
        int j = i * 256 + t;
        orow[j] = f2bf((v[i] - mu) * r * lnw[j] + lnb[j]);
    }
}

// ---- global attention: split-K (2 waves/query-group), 4 Q-frags/wave, pinned prefetch --
// qT: [B*8][4096][32] bf16 (SCALE*log2e folded); kT: [B*8][1024][32]; vT: [B*8][32][1024]
// (vperm'd key positions). Reads gxT, writes projT = bf16(gxT + O) p-major.
// Block = 4 waves: wave w -> query-group qg=w>>1 (64 q), K-half kh=w&1 (512 keys).
// Fixed-max softmax => partial (O, l) merge is a pure add (LDS combine, one barrier).
__global__ __launch_bounds__(256, 4) void global_attn_mfma(
    const unsigned short* __restrict__ qT,
    const unsigned short* __restrict__ kT,
    const unsigned short* __restrict__ vT,
    const unsigned short* __restrict__ gxT,
    unsigned short* __restrict__ projT)
{
    int blk = blockIdx.x;               // b*256 + h*32 + qt2  (1024 blocks)
    int qt2 = blk & 31, h = (blk >> 5) & 7, b = blk >> 8;
    int bh = b * 8 + h;
    int w = threadIdx.x >> 6, lane = threadIdx.x & 63;
    int qg = w >> 1, kh = w & 1;
    int m = lane & 15, g = lane >> 4;
    int qbase = qt2 * 128 + qg * 64;

    __shared__ float comb[2][64][37];   // [pair][lane][32 O + 4 l], stride 37 (bank-spread)

    const unsigned short* qp = qT + ((size_t)bh * 4096 + qbase + m) * 32 + g * 8;
    v8s qf0 = *(const v8s*)(qp);
    v8s qf1 = *(const v8s*)(qp + 16 * 32);
    v8s qf2 = *(const v8s*)(qp + 32 * 32);
    v8s qf3 = *(const v8s*)(qp + 48 * 32);

    const v4f zf = {0.f, 0.f, 0.f, 0.f};
    v4f o00 = zf, o01 = zf, o10 = zf, o11 = zf;
    v4f o20 = zf, o21 = zf, o30 = zf, o31 = zf;
    float l0 = 0.f, l1 = 0.f, l2 = 0.f, l3 = 0.f;

    const unsigned short* kbase = kT + ((size_t)(bh * 1024 + kh * 512) + m) * 32 + g * 8;
    const unsigned short* vbase = vT + ((size_t)bh * 32 + m) * 1024 + kh * 512 + g * 8;

    // prologue: tile 0 into current regs
    v8s ka0 = *(const v8s*)(kbase);
    v8s ka1 = *(const v8s*)(kbase + 16 * 32);
    v8s ka2 = *(const v8s*)(kbase + 32 * 32);
    v8s ka3 = *(const v8s*)(kbase + 48 * 32);
    v8s vb0 = *(const v8s*)(vbase);
    v8s vb1 = *(const v8s*)(vbase + 16 * 1024);
    v8s vb2 = *(const v8s*)(vbase + 32);
    v8s vb3 = *(const v8s*)(vbase + 32 + 16 * 1024);

    #pragma unroll 2
    for (int t = 0; t < 8; t++) {
        // prefetch tile t+1 (last iter re-loads tile 7; harmless)
        int kn = (t < 7 ? t + 1 : 7) * 64;
        const unsigned short* kp = kbase + (size_t)kn * 32;
        const unsigned short* vp = vbase + kn;
        v8s nk0 = *(const v8s*)(kp);
        v8s nk1 = *(const v8s*)(kp + 16 * 32);
        v8s nk2 = *(const v8s*)(kp + 32 * 32);
        v8s nk3 = *(const v8s*)(kp + 48 * 32);
        v8s nv0 = *(const v8s*)(vp);
        v8s nv1 = *(const v8s*)(vp + 16 * 1024);
        v8s nv2 = *(const v8s*)(vp + 32);
        v8s nv3 = *(const v8s*)(vp + 32 + 16 * 1024);
        // pin: prefetch loads must be issued before the compute below
        __builtin_amdgcn_sched_barrier(0);

        // qi = 0
        {
            v4f s0 = __builtin_amdgcn_mfma_f32_16x16x32_bf16(ka0, qf0, zf, 0, 0, 0);
            v4f s1 = __builtin_amdgcn_mfma_f32_16x16x32_bf16(ka1, qf0, zf, 0, 0, 0);
            v4f s2 = __builtin_amdgcn_mfma_f32_16x16x32_bf16(ka2, qf0, zf, 0, 0, 0);
            v4f s3 = __builtin_amdgcn_mfma_f32_16x16x32_bf16(ka3, qf0, zf, 0, 0, 0);
            uint2 a0 = expack2(s0, l0), a1 = expack2(s1, l0);
            uint2 a2 = expack2(s2, l0), a3 = expack2(s3, l0);
            v8s pa0 = u4v8(a0, a1), pa1 = u4v8(a2, a3);
            o00 = __builtin_amdgcn_mfma_f32_16x16x32_bf16(pa0, vb0, o00, 0, 0, 0);
            o01 = __builtin_amdgcn_mfma_f32_16x16x32_bf16(pa0, vb1, o01, 0, 0, 0);
            o00 = __builtin_amdgcn_mfma_f32_16x16x32_bf16(pa1, vb2, o00, 0, 0, 0);
            o01 = __builtin_amdgcn_mfma_f32_16x16x32_bf16(pa1, vb3, o01, 0, 0, 0);
        }
        // qi = 1
        {
            v4f s0 = __builtin_amdgcn_mfma_f32_16x16x32_bf16(ka0, qf1, zf, 0, 0, 0);
            v4f s1 = __builtin_amdgcn_mfma_f32_16x16x32_bf16(ka1, qf1, zf, 0, 0, 0);
            v4f s2 = __builtin_amdgcn_mfma_f32_16x16x32_bf16(ka2, qf1, zf, 0, 0, 0);
            v4f s3 = __builtin_amdgcn_mfma_f32_16x16x32_bf16(ka3, qf1, zf, 0, 0, 0);
            uint2 a0 = expack2(s0, l1), a1 = expack2(s1, l1);
            uint2 a2 = expack2(s2, l1), a3 = expack2(s3, l1);
            v8s pa0 = u4v8(a0, a1), pa1 = u4v8(a2, a3);
            o10 = __builtin_amdgcn_mfma_f32_16x16x32_bf16(pa0, vb0, o10, 0, 0, 0);
            o11 = __builtin_amdgcn_mfma_f32_16x16x32_bf16(pa0, vb1, o11, 0, 0, 0);
            o10 = __builtin_amdgcn_mfma_f32_16x16x32_bf16(pa1, vb2, o10, 0, 0, 0);
            o11 = __builtin_amdgcn_mfma_f32_16x16x32_bf16(pa1, vb3, o11, 0, 0, 0);
        }
        // qi = 2
        {
            v4f s0 = __builtin_amdgcn_mfma_f32_16x16x32_bf16(ka0, qf2, zf, 0, 0, 0);
            v4f s1 = __builtin_amdgcn_mfma_f32_16x16x32_bf16(ka1, qf2, zf, 0, 0, 0);
            v4f s2 = __builtin_amdgcn_mfma_f32_16x16x32_bf16(ka2, qf2, zf, 0, 0, 0);
            v4f s3 = __builtin_amdgcn_mfma_f32_16x16x32_bf16(ka3, qf2, zf, 0, 0, 0);
            uint2 a0 = expack2(s0, l2), a1 = expack2(s1, l2);
            uint2 a2 = expack2(s2, l2), a3 = expack2(s3, l2);
            v8s pa0 = u4v8(a0, a1), pa1 = u4v8(a2, a3);
            o20 = __builtin_amdgcn_mfma_f32_16x16x32_bf16(pa0, vb0, o20, 0, 0, 0);
            o21 = __builtin_amdgcn_mfma_f32_16x16x32_bf16(pa0, vb1, o21, 0, 0, 0);
            o20 = __builtin_amdgcn_mfma_f32_16x16x32_bf16(pa1, vb2, o20, 0, 0, 0);
            o21 = __builtin_amdgcn_mfma_f32_16x16x32_bf16(pa1, vb3, o21, 0, 0, 0);
        }
        // qi = 3
        {
            v4f s0 = __builtin_amdgcn_mfma_f32_16x16x32_bf16(ka0, qf3, zf, 0, 0, 0);
            v4f s1 = __builtin_amdgcn_mfma_f32_16x16x32_bf16(ka1, qf3, zf, 0, 0, 0);
            v4f s2 = __builtin_amdgcn_mfma_f32_16x16x32_bf16(ka2, qf3, zf, 0, 0, 0);
            v4f s3 = __builtin_amdgcn_mfma_f32_16x16x32_bf16(ka3, qf3, zf, 0, 0, 0);
            uint2 a0 = expack2(s0, l3), a1 = expack2(s1, l3);
            uint2 a2 = expack2(s2, l3), a3 = expack2(s3, l3);
            v8s pa0 = u4v8(a0, a1), pa1 = u4v8(a2, a3);
            o30 = __builtin_amdgcn_mfma_f32_16x16x32_bf16(pa0, vb0, o30, 0, 0, 0);
            o31 = __builtin_amdgcn_mfma_f32_16x16x32_bf16(pa0, vb1, o31, 0, 0, 0);
            o30 = __builtin_amdgcn_mfma_f32_16x16x32_bf16(pa1, vb2, o30, 0, 0, 0);
            o31 = __builtin_amdgcn_mfma_f32_16x16x32_bf16(pa1, vb3, o31, 0, 0, 0);
        }

        ka0 = nk0; ka1 = nk1; ka2 = nk2; ka3 = nk3;
        vb0 = nv0; vb1 = nv1; vb2 = nv2; vb3 = nv3;
    }

    // split-K combine: kh=1 waves publish partials; kh=0 waves merge and finish
    if (kh == 1) {
        float* c = comb[qg][lane];
        *(v4f*)(c + 0)  = o00; *(v4f*)(c + 4)  = o01;
        *(v4f*)(c + 8)  = o10; *(v4f*)(c + 12) = o11;
        *(v4f*)(c + 16) = o20; *(v4f*)(c + 20) = o21;
        *(v4f*)(c + 24) = o30; *(v4f*)(c + 28) = o31;
        c[32] = l0; c[33] = l1; c[34] = l2; c[35] = l3;
    }
    __syncthreads();
    if (kh == 1) return;

    {
        const float* c = comb[qg][lane];
        o00 += *(const v4f*)(c + 0);  o01 += *(const v4f*)(c + 4);
        o10 += *(const v4f*)(c + 8);  o11 += *(const v4f*)(c + 12);
        o20 += *(const v4f*)(c + 16); o21 += *(const v4f*)(c + 20);
        o30 += *(const v4f*)(c + 24); o31 += *(const v4f*)(c + 28);
        l0 += c[32]; l1 += c[33]; l2 += c[34]; l3 += c[35];
    }

    float lf[4] = {l0, l1, l2, l3};
    v4f oq0[4] = {o00, o10, o20, o30};
    v4f oq1[4] = {o01, o11, o21, o31};
    #pragma unroll
    for (int qi = 0; qi < 4; qi++) {
        float lfq = lf[qi];
        lfq += __shfl_xor(lfq, 16);
        lfq += __shfl_xor(lfq, 32);
        float inv = 1.f / lfq;
        float invq[4];
        #pragma unroll
        for (int r = 0; r < 4; r++) invq[r] = __shfl(inv, g * 4 + r);
        #pragma unroll
        for (int r = 0; r < 4; r++) {
            size_t row = ((size_t)b * 4096 + qbase + qi * 16 + g * 4 + r) * 256 + h * 32;
            projT[row + m]      = f2bf(bf2f(gxT[row + m])      + oq0[qi][r] * invq[r]);
            projT[row + 16 + m] = f2bf(bf2f(gxT[row + 16 + m]) + oq1[qi][r] * invq[r]);
        }
    }
}

// ---------------- launcher ----------------
extern "C" void kernel_launch(void* const* d_in, const int* in_sizes, int n_in,
                              void* d_out, int out_size, void* d_ws, size_t ws_size,
                              hipStream_t stream)
{
    const float* x           = (const float*)d_in[0];
    const float* norm_w      = (const float*)d_in[1];
    const float* norm_b      = (const float*)d_in[2];
    const float* qkv_w       = (const float*)d_in[3];
    const float* qkv_b       = (const float*)d_in[4];
    const float* proj_w      = (const float*)d_in[5];
    const float* proj_b      = (const float*)d_in[6];
    const float* grid_norm_w = (const float*)d_in[7];
    const float* grid_norm_b = (const float*)d_in[8];
    const float* pm_ln_w     = (const float*)d_in[9];
    const float* pm_ln_b     = (const float*)d_in[10];
    const float* pm_red_w    = (const float*)d_in[11];
    const float* ds_norm_w   = (const float*)d_in[12];
    const float* ds_norm_b   = (const float*)d_in[13];
    const float* q_w         = (const float*)d_in[14];
    const float* q_b         = (const float*)d_in[15];
    const float* kv_w        = (const float*)d_in[16];
    const float* kv_b        = (const float*)d_in[17];
    float* out = (float*)d_out;

    float* wsf = (float*)d_ws;
    unsigned short* qkp   = (unsigned short*)(wsf);
    unsigned short* vbb   = (unsigned short*)(wsf + 4194304);
    unsigned short* mnb   = (unsigned short*)(wsf);
    unsigned short* kTu   = (unsigned short*)(wsf);
    unsigned short* vTu   = (unsigned short*)(wsf + 524288);
    float* pm             = wsf + 2097152;
    unsigned short* pmT   = (unsigned short*)(wsf + 3145728);
    unsigned short* qTu   = (unsigned short*)(wsf + 10485760);
    unsigned short* gxb   = (unsigned short*)(wsf + 12582912);
    unsigned short* projT = (unsigned short*)(wsf + 12582912);  // gxb dead before step 12
    unsigned short* xT    = (unsigned short*)(wsf + 16777216);
    unsigned short* gxT   = (unsigned short*)(wsf + 16777216);
    float* part   = wsf + 18874368;
    unsigned short* wbf   = (unsigned short*)(wsf + 18875392);
    unsigned short* wbf_qkv  = wbf;
    unsigned short* wbf_pm   = wbf + 196608;
    unsigned short* wbf_kv   = wbf + 458752;
    unsigned short* wbf_q    = wbf + 589824;
    unsigned short* wbf_proj = wbf + 655360;

    // 1. weights -> bf16  +  partial stats of x (fused, independent block ranges)
    prep_kernel<<<960, 256, 0, stream>>>(qkv_w, pm_red_w, kv_w, q_w, proj_w, wbf, x, part);
    // 2. xT = bf16(GN(x)) p-major (stats finalized inline)
    tnc<<<dim3(64, 4, BATCH), 256, 0, stream>>>(
        x, nullptr, part, 64, 1.f / 1048576.f, EPS_GN, norm_w, norm_b, xT, 4096);
    // 3. qkv GEMM (MFMA 128x128) -> qkp + vbb
    gemm_bf16<1><<<dim3(32, 6, BATCH), 256, 0, stream>>>(
        xT, wbf_qkv, qkv_b, nullptr, qkp, vbb, nullptr, 256, 4096, 768, 1.f);
    // 4. local windowed attention (MFMA, LDS-free) -> gxb bf16 c-major
    local_attn_mfma<<<2048, 256, 0, stream>>>(qkp, vbb, gxb);
    // 5. partial stats of x+gx
    gn_partial4<<<BATCH * 64, 256, 0, stream>>>(x, gxb, 262144, 64, part);
    // 6. gxT = bf16(GN(x+gx)) p-major
    tnc<<<dim3(64, 4, BATCH), 256, 0, stream>>>(
        x, gxb, part, 64, 1.f / 1048576.f, EPS_GN, grid_norm_w, grid_norm_b, gxT, 4096);
    // 7. patch-merge LN -> mn bf16
    patch_merge_ln2<<<4096, 256, 0, stream>>>(gxT, pm_ln_w, pm_ln_b, mnb);
    // 8. patch-merge reduction GEMM (MFMA 128x128) + fused GN stage-1 partials
    gemm_bf16<0><<<dim3(8, 2, BATCH), 256, 0, stream>>>(
        mnb, wbf_pm, nullptr, pm, nullptr, nullptr, part, 1024, 1024, 256, 1.f);
    // 9. pmT = bf16(GN(pm)) p-major (nblk = 16 tiles/batch from step 8)
    tnc<<<dim3(16, 4, BATCH), 256, 0, stream>>>(
        pm, nullptr, part, 16, 1.f / 262144.f, EPS_GN, ds_norm_w, ds_norm_b, pmT, 1024);
    // 10. kv GEMM (MFMA 128x128) -> kTu (p-major) + vTu (c-major, vperm'd)
    gemm_bf16<3><<<dim3(8, 4, BATCH), 256, 0, stream>>>(
        pmT, wbf_kv, kv_b, nullptr, kTu, vTu, nullptr, 256, 1024, 512, 1.f);
    // 11. q GEMM (MFMA 128x128) -> qTu (head-split p-major, SCALE*log2e folded)
    gemm_bf16<2><<<dim3(32, 2, BATCH), 256, 0, stream>>>(
        gxT, wbf_q, q_b, nullptr, qTu, nullptr, nullptr, 256, 4096, 256, SCL2);
    // 12. global attention (MFMA, split-K 2 waves/query-group) -> projT = bf16(gxT + O)
    global_attn_mfma<<<1024, 256, 0, stream>>>(qTu, kTu, vTu, gxT, projT);
    // 13. proj GEMM (MFMA 128x128) -> out
    gemm_bf16<0><<<dim3(32, 2, BATCH), 256, 0, stream>>>(
        projT, wbf_proj, proj_b, out, nullptr, nullptr, nullptr, 256, 4096, 256, 1.f);
}

// Round 17
// 156.042 us; speedup vs baseline: 1.5964x; 1.5964x over previous
//
#include <hip/hip_runtime.h>
#include <hip/hip_bf16.h>

// Problem constants
#define BATCH 4
#define CDIM 256
#define HWSZ 4096          // 64*64
#define P2 1024            // 32*32 pooled pixels per batch
#define SCALE 0.17677669529663687f
#define LOG2E 1.4426950408889634f
#define SCL2 (SCALE * LOG2E)
#define EPS_GN 1e-6f
#define EPS_LN 1e-5f
#define MFIX 8.0f          // fixed softmax shift (scores are O(1); exp(s-8) can't overflow)
#define MFIX2 (MFIX * LOG2E)

typedef short v8s __attribute__((ext_vector_type(8)));
typedef float v4f __attribute__((ext_vector_type(4)));

__device__ __forceinline__ unsigned short f2bf(float f) {
    __hip_bfloat16 h = __float2bfloat16(f);
    return *reinterpret_cast<unsigned short*>(&h);
}
__device__ __forceinline__ float bf2f(unsigned short u) {
    return __uint_as_float(((unsigned int)u) << 16);
}
__device__ __forceinline__ float bflo(unsigned int u) {
    return __uint_as_float(u << 16);
}
__device__ __forceinline__ float bfhi(unsigned int u) {
    return __uint_as_float(u & 0xffff0000u);
}
__device__ __forceinline__ unsigned int pack2(float lo, float hi) {
    return (unsigned int)f2bf(lo) | ((unsigned int)f2bf(hi) << 16);
}
// truncating bf16 pack (P-values only: softmax ratio cancels the truncation bias)
__device__ __forceinline__ unsigned int tpack2(float lo, float hi) {
    return (__float_as_uint(lo) >> 16) | (__float_as_uint(hi) & 0xffff0000u);
}
__device__ __forceinline__ float fexp2(float x) {
#if __has_builtin(__builtin_amdgcn_exp2f)
    return __builtin_amdgcn_exp2f(x);
#else
    return exp2f(x);
#endif
}
// 2^(s-MFIX2) for 4 log2-domain scores -> packed 4xbf16 (truncated), accumulating sum
__device__ __forceinline__ uint2 expack2(v4f s, float& sum) {
    float a = fexp2(s[0] - MFIX2);
    float b = fexp2(s[1] - MFIX2);
    float c = fexp2(s[2] - MFIX2);
    float d = fexp2(s[3] - MFIX2);
    sum += (a + b) + (c + d);
    return make_uint2(tpack2(a, b), tpack2(c, d));
}
__device__ __forceinline__ v8s u4v8(uint2 a, uint2 b) {
    union { unsigned int u[4]; v8s v; } r;
    r.u[0] = a.x; r.u[1] = a.y; r.u[2] = b.x; r.u[3] = b.y;
    return r.v;
}
// V key permutation within a 64-key block: S^T reg order -> PV A-frag contract order.
__device__ __forceinline__ int vperm(int j) {
    return (j & 0x23) | ((j & 0x0C) << 1) | ((j & 0x10) >> 2);
}
__device__ __forceinline__ void async16(void* lds, const void* g) {
    __builtin_amdgcn_global_load_lds(
        (const __attribute__((address_space(1))) unsigned int*)g,
        (__attribute__((address_space(3))) unsigned int*)lds, 16, 0, 0);
}

// ------- prep: weight cast (blocks 0..703) + GN partial stats of x (blocks 704..959) ----
__global__ void prep_kernel(const float* __restrict__ w0, const float* __restrict__ w1,
                            const float* __restrict__ w2, const float* __restrict__ w3,
                            const float* __restrict__ w4, unsigned short* __restrict__ dst,
                            const float* __restrict__ x, float* __restrict__ part)
{
    int bid = blockIdx.x;
    int tid = threadIdx.x;
    if (bid < 704) {
        int idx = (bid * 256 + tid) * 4;
        const float* src; int off;
        if      (idx < 196608) { src = w0; off = 0; }
        else if (idx < 458752) { src = w1; off = 196608; }
        else if (idx < 589824) { src = w2; off = 458752; }
        else if (idx < 655360) { src = w3; off = 589824; }
        else                   { src = w4; off = 655360; }
        float4 v = *(const float4*)(src + idx - off);
        *(uint2*)(dst + idx) = make_uint2(pack2(v.x, v.y), pack2(v.z, v.w));
        return;
    }
    // x stats: 256 blocks, nblk=64 per batch, pb4=262144
    int blk2 = bid - 704;
    int bb = blk2 >> 6, blk = blk2 & 63;
    const float* pa = x + (size_t)bb * 1048576;
    float s = 0.f, s2 = 0.f;
    for (int i = blk * 256 + tid; i < 262144; i += 64 * 256) {
        float4 v = *(const float4*)(pa + (size_t)i * 4);
        s += (v.x + v.y) + (v.z + v.w);
        s2 += fmaf(v.x, v.x, fmaf(v.y, v.y, fmaf(v.z, v.z, v.w * v.w)));
    }
    __shared__ float ls[256], ls2[256];
    ls[tid] = s; ls2[tid] = s2; __syncthreads();
    for (int off = 128; off > 0; off >>= 1) {
        if (tid < off) { ls[tid] += ls[tid + off]; ls2[tid] += ls2[tid + off]; }
        __syncthreads();
    }
    if (tid == 0) {
        part[blk2 * 2]     = ls[0];
        part[blk2 * 2 + 1] = ls2[0];
    }
}

// ---------------- GroupNorm partial stats (fp32 a + optional bf16 addend) ----------
__global__ void gn_partial4(const float* __restrict__ a, const unsigned short* __restrict__ a2bf,
                            int pb4, int nblk, float* __restrict__ part)
{
    int bb  = blockIdx.x / nblk;
    int blk = blockIdx.x % nblk;
    const float* pa = a + (size_t)bb * pb4 * 4;
    const unsigned short* pa2 = a2bf ? a2bf + (size_t)bb * pb4 * 4 : nullptr;
    int tid = threadIdx.x;
    float s = 0.f, s2 = 0.f;
    for (int i = blk * 256 + tid; i < pb4; i += nblk * 256) {
        float4 v = *(const float4*)(pa + (size_t)i * 4);
        if (pa2) {
            uint2 g = *(const uint2*)(pa2 + (size_t)i * 4);
            v.x += bflo(g.x); v.y += bfhi(g.x);
            v.z += bflo(g.y); v.w += bfhi(g.y);
        }
        s += (v.x + v.y) + (v.z + v.w);
        s2 += fmaf(v.x, v.x, fmaf(v.y, v.y, fmaf(v.z, v.z, v.w * v.w)));
    }
    __shared__ float ls[256], ls2[256];
    ls[tid] = s; ls2[tid] = s2; __syncthreads();
    for (int off = 128; off > 0; off >>= 1) {
        if (tid < off) { ls[tid] += ls[tid + off]; ls2[tid] += ls2[tid + off]; }
        __syncthreads();
    }
    if (tid == 0) {
        part[blockIdx.x * 2]     = ls[0];
        part[blockIdx.x * 2 + 1] = ls2[0];
    }
}

// ------- transpose + (optional bf16 add) + norm (stats finalized inline) + cast ---------
// A: [b][256][P] fp32 c-major.  A2b: optional bf16 addend same layout.  dst: [b][P][256] bf16.
__global__ __launch_bounds__(256) void tnc(
    const float* __restrict__ A, const unsigned short* __restrict__ A2b,
    const float* __restrict__ part, int nblk, float inv_n, float eps,
    const float* __restrict__ nw, const float* __restrict__ nb,
    unsigned short* __restrict__ dst, int P)
{
    int b = blockIdx.z, c0 = blockIdx.y * 64, p0 = blockIdx.x * 64;
    __shared__ float ld[64][65];
    __shared__ float sstat[2];
    int t = threadIdx.x;
    if (t < 64) {
        float s = 0.f, s2 = 0.f;
        if (t < nblk) {
            s  = part[(b * nblk + t) * 2];
            s2 = part[(b * nblk + t) * 2 + 1];
        }
        #pragma unroll
        for (int off = 32; off > 0; off >>= 1) {
            s  += __shfl_down(s, off);
            s2 += __shfl_down(s2, off);
        }
        if (t == 0) {
            float mval = s * inv_n;
            float var  = s2 * inv_n - mval * mval;
            sstat[0] = mval;
            sstat[1] = rsqrtf(var + eps);
        }
    }
    __syncthreads();
    float mean = sstat[0], rstd = sstat[1];
    {
        int ch = t >> 2, pq = (t & 3) * 16;
        size_t base = ((size_t)b * 256 + c0 + ch) * P + p0 + pq;
        float4 f0 = *(const float4*)(A + base);
        float4 f1 = *(const float4*)(A + base + 4);
        float4 f2 = *(const float4*)(A + base + 8);
        float4 f3 = *(const float4*)(A + base + 12);
        if (A2b) {
            const unsigned short* ap = A2b + base;
            uint4 q0 = *(const uint4*)(ap);
            uint4 q1 = *(const uint4*)(ap + 8);
            f0.x += bflo(q0.x); f0.y += bfhi(q0.x); f0.z += bflo(q0.y); f0.w += bfhi(q0.y);
            f1.x += bflo(q0.z); f1.y += bfhi(q0.z); f1.z += bflo(q0.w); f1.w += bfhi(q0.w);
            f2.x += bflo(q1.x); f2.y += bfhi(q1.x); f2.z += bflo(q1.y); f2.w += bfhi(q1.y);
            f3.x += bflo(q1.z); f3.y += bfhi(q1.z); f3.z += bflo(q1.w); f3.w += bfhi(q1.w);
        }
        float wv = nw[c0 + ch];
        float sw = rstd * wv;
        float sb = nb[c0 + ch] - mean * rstd * wv;
        ld[ch][pq + 0]  = f0.x * sw + sb; ld[ch][pq + 1]  = f0.y * sw + sb;
        ld[ch][pq + 2]  = f0.z * sw + sb; ld[ch][pq + 3]  = f0.w * sw + sb;
        ld[ch][pq + 4]  = f1.x * sw + sb; ld[ch][pq + 5]  = f1.y * sw + sb;
        ld[ch][pq + 6]  = f1.z * sw + sb; ld[ch][pq + 7]  = f1.w * sw + sb;
        ld[ch][pq + 8]  = f2.x * sw + sb; ld[ch][pq + 9]  = f2.y * sw + sb;
        ld[ch][pq + 10] = f2.z * sw + sb; ld[ch][pq + 11] = f2.w * sw + sb;
        ld[ch][pq + 12] = f3.x * sw + sb; ld[ch][pq + 13] = f3.y * sw + sb;
        ld[ch][pq + 14] = f3.z * sw + sb; ld[ch][pq + 15] = f3.w * sw + sb;
    }
    __syncthreads();
    {
        int p = t >> 2, cb = (t & 3) * 16;
        unsigned int u[8];
        #pragma unroll
        for (int j = 0; j < 8; j++)
            u[j] = pack2(ld[cb + 2 * j][p], ld[cb + 2 * j + 1][p]);
        unsigned short* dp = dst + ((size_t)b * P + p0 + p) * 256 + c0 + cb;
        *(uint4*)(dp)     = make_uint4(u[0], u[1], u[2], u[3]);
        *(uint4*)(dp + 8) = make_uint4(u[4], u[5], u[6], u[7]);
    }
}

// ---------------- MFMA GEMM (128x128 tile): OUT = actT * W^T + bias ----------
// MODE 0: OUT fp32 c-major [B][OC][P]; optional partOut: per-block (sum,sumsq) partials.
// MODE 1: qkv split -> aux1 = qkp bf16 [B][4096][512] p-major (ch<512);
//         ch>=512 (V) -> aux2 bf16 c-major [B][256][4096].
// MODE 2: head-split p-major bf16 [B*8][P][32], (acc+bias)*oscale  (Q path).
// MODE 3: kv: ch<256 (K) -> aux1 [B*8][1024][32] p-major; ch>=256 (V) -> aux2 [B*8][32][1024]
//         c-major with vperm'd key positions.
template<int MODE>
__global__ __launch_bounds__(256, 3) void gemm_bf16(
    const unsigned short* __restrict__ actT,
    const unsigned short* __restrict__ Wb,
    const float* __restrict__ bias,
    float* __restrict__ out,
    unsigned short* __restrict__ aux1,
    unsigned short* __restrict__ aux2,
    float* __restrict__ partOut,
    int K, int P, int OC, float oscale)
{
    int b  = blockIdx.z;
    int p0 = blockIdx.x * 128;
    int m0 = blockIdx.y * 128;
    int tid = threadIdx.x;
    int w = tid >> 6, lane = tid & 63;
    int lm = lane & 15, lg = lane >> 4;
    int wm = w >> 1, wp = w & 1;
    int l8 = lane >> 3, cc = lane & 7;

    __shared__ __align__(16) unsigned short Wt[128 * 64];   // [m][64k], swizzled
    __shared__ __align__(16) unsigned short At[128 * 64];   // [p][64k], swizzled

    const unsigned short* actB = actT + (size_t)b * P * K;

    v4f acc[4][4];
    #pragma unroll
    for (int i = 0; i < 4; i++)
        #pragma unroll
        for (int j = 0; j < 4; j++) acc[i][j] = (v4f){0.f, 0.f, 0.f, 0.f};

    for (int ks = 0; ks < K; ks += 64) {
        #pragma unroll
        for (int i = 0; i < 4; i++) {
            int ml = w * 32 + i * 8 + l8;
            int g = cc ^ (ml & 7);
            async16(&Wt[ml * 64], Wb + (size_t)(m0 + ml) * K + ks + g * 8);
        }
        #pragma unroll
        for (int i = 0; i < 4; i++) {
            int pl = w * 32 + i * 8 + l8;
            int g = cc ^ (pl & 7);
            async16(&At[pl * 64], actB + (size_t)(p0 + pl) * K + ks + g * 8);
        }
        __syncthreads();
        #pragma unroll
        for (int kk = 0; kk < 2; kk++) {
            v8s af[4], bfv[4];
            #pragma unroll
            for (int mt = 0; mt < 4; mt++) {
                int m = wm * 64 + mt * 16 + lm;
                int ch = (kk * 4 + lg) ^ (m & 7);
                af[mt] = *(const v8s*)&Wt[m * 64 + ch * 8];
            }
            #pragma unroll
            for (int pt = 0; pt < 4; pt++) {
                int p = wp * 64 + pt * 16 + lm;
                int ch = (kk * 4 + lg) ^ (p & 7);
                bfv[pt] = *(const v8s*)&At[p * 64 + ch * 8];
            }
            #pragma unroll
            for (int mt = 0; mt < 4; mt++)
                #pragma unroll
                for (int pt = 0; pt < 4; pt++)
                    acc[mt][pt] = __builtin_amdgcn_mfma_f32_16x16x32_bf16(
                        af[mt], bfv[pt], acc[mt][pt], 0, 0, 0);
        }
        __syncthreads();
    }

    if constexpr (MODE == 1) {
        if (m0 < 512) {
            #pragma unroll
            for (int mt = 0; mt < 4; mt++) {
                int mch = m0 + wm * 64 + mt * 16 + lg * 4;
                float4 bs = *(const float4*)(bias + mch);
                #pragma unroll
                for (int pt = 0; pt < 4; pt++) {
                    int p = p0 + wp * 64 + pt * 16 + lm;
                    unsigned int u0 = pack2(acc[mt][pt][0] + bs.x, acc[mt][pt][1] + bs.y);
                    unsigned int u1 = pack2(acc[mt][pt][2] + bs.z, acc[mt][pt][3] + bs.w);
                    *(uint2*)(aux1 + ((size_t)(b * 4096 + p) * 512 + mch)) = make_uint2(u0, u1);
                }
            }
        } else {
            // V -> bf16 c-major [b][256][4096]
            #pragma unroll
            for (int mt = 0; mt < 4; mt++) {
                #pragma unroll
                for (int r = 0; r < 4; r++) {
                    int mch = m0 + wm * 64 + mt * 16 + lg * 4 + r;
                    float bsv = bias[mch];
                    unsigned short* orow = aux2 + ((size_t)b * 256 + (mch - 512)) * 4096
                                           + p0 + wp * 64;
                    #pragma unroll
                    for (int pt = 0; pt < 4; pt++)
                        orow[pt * 16 + lm] = f2bf(acc[mt][pt][r] + bsv);
                }
            }
        }
    } else if constexpr (MODE == 2) {
        #pragma unroll
        for (int mt = 0; mt < 4; mt++) {
            int ch = m0 + wm * 64 + mt * 16 + lg * 4;
            int head = ch >> 5, d = ch & 31;
            float4 bs = *(const float4*)(bias + ch);
            #pragma unroll
            for (int pt = 0; pt < 4; pt++) {
                int p = p0 + wp * 64 + pt * 16 + lm;
                unsigned int u0 = pack2((acc[mt][pt][0] + bs.x) * oscale,
                                        (acc[mt][pt][1] + bs.y) * oscale);
                unsigned int u1 = pack2((acc[mt][pt][2] + bs.z) * oscale,
                                        (acc[mt][pt][3] + bs.w) * oscale);
                *(uint2*)(aux1 + ((size_t)(b * 8 + head) * P + p) * 32 + d) = make_uint2(u0, u1);
            }
        }
    } else if constexpr (MODE == 3) {
        #pragma unroll
        for (int mt = 0; mt < 4; mt++) {
            int ch = m0 + wm * 64 + mt * 16 + lg * 4;
            if (ch < 256) {     // K -> p-major [bh][1024][32]
                int head = ch >> 5, d = ch & 31;
                float4 bs = *(const float4*)(bias + ch);
                #pragma unroll
                for (int pt = 0; pt < 4; pt++) {
                    int p = p0 + wp * 64 + pt * 16 + lm;
                    unsigned int u0 = pack2(acc[mt][pt][0] + bs.x, acc[mt][pt][1] + bs.y);
                    unsigned int u1 = pack2(acc[mt][pt][2] + bs.z, acc[mt][pt][3] + bs.w);
                    *(uint2*)(aux1 + ((size_t)(b * 8 + head) * P + p) * 32 + d) = make_uint2(u0, u1);
                }
            } else {            // V -> c-major [bh][32][1024], vperm'd positions
                int v = ch - 256;
                int head = v >> 5, d0 = v & 31;
                #pragma unroll
                for (int pt = 0; pt < 4; pt++) {
                    int p = p0 + wp * 64 + pt * 16 + lm;
                    int pos = (p & ~63) | vperm(p & 63);
                    #pragma unroll
                    for (int r = 0; r < 4; r++)
                        aux2[((size_t)(b * 8 + head) * 32 + d0 + r) * P + pos] =
                            f2bf(acc[mt][pt][r] + bias[ch + r]);
                }
            }
        }
    } else {
        float s = 0.f, s2 = 0.f;
        #pragma unroll
        for (int mt = 0; mt < 4; mt++) {
            #pragma unroll
            for (int r = 0; r < 4; r++) {
                int m = m0 + wm * 64 + mt * 16 + lg * 4 + r;
                float bs = bias ? bias[m] : 0.f;
                float* orow = out + (size_t)b * OC * P + (size_t)m * P + p0 + wp * 64;
                #pragma unroll
                for (int pt = 0; pt < 4; pt++) {
                    float v = acc[mt][pt][r] + bs;
                    orow[pt * 16 + lm] = v;
                    s += v; s2 = fmaf(v, v, s2);
                }
            }
        }
        if (partOut) {
            __shared__ float rs[256], rs2[256];
            rs[tid] = s; rs2[tid] = s2; __syncthreads();
            for (int off = 128; off > 0; off >>= 1) {
                if (tid < off) { rs[tid] += rs[tid + off]; rs2[tid] += rs2[tid + off]; }
                __syncthreads();
            }
            if (tid == 0) {
                int tilesPB = gridDim.x * gridDim.y;
                int tile = blockIdx.y * gridDim.x + blockIdx.x;
                partOut[((size_t)b * tilesPB + tile) * 2]     = rs[0];
                partOut[((size_t)b * tilesPB + tile) * 2 + 1] = rs2[0];
            }
        }
    }
}

// ---------------- local windowed attention, bf16 MFMA, fixed-max, LDS-free ----------------
// qkp: [B][4096][512] bf16 (Q ch 0-255, K ch 256-511); vbb: [B][256][4096] bf16 c-major.
// gxb: [B][256][4096] bf16 c-major output.
__global__ __launch_bounds__(256, 4) void local_attn_mfma(
    const unsigned short* __restrict__ qkp,
    const unsigned short* __restrict__ vbb,
    unsigned short* __restrict__ gxb)
{
    int win = blockIdx.x;                  // b*512 + h*64 + gy*8 + gxc
    int gxc = win & 7, gy = (win >> 3) & 7, h = (win >> 6) & 7, b = win >> 9;
    int w = threadIdx.x >> 6, lane = threadIdx.x & 63;
    int m = lane & 15, g = lane >> 4;

    int rowbase = (gy * 8) * 64 + gxc * 8;   // pixel of window token 0
    const unsigned short* qkb = qkp + (size_t)b * 4096 * 512;
    const unsigned short* vbase = vbb + (size_t)b * 256 * 4096;

    int tq = w * 16 + m;
    int pq = rowbase + (tq >> 3) * 64 + (tq & 7);
    v8s qf = *(const v8s*)(qkb + (size_t)pq * 512 + h * 32 + g * 8);

    v8s ka[4];
    #pragma unroll
    for (int kt = 0; kt < 4; kt++) {
        int tk = kt * 16 + m;
        int pk = rowbase + (tk >> 3) * 64 + (tk & 7);
        ka[kt] = *(const v8s*)(qkb + (size_t)pk * 512 + 256 + h * 32 + g * 8);
    }
    v8s vb[2][2];
    #pragma unroll
    for (int c = 0; c < 2; c++)
        #pragma unroll
        for (int dt = 0; dt < 2; dt++) {
            const unsigned short* vp = vbase + (size_t)(h * 32 + dt * 16 + m) * 4096
                              + rowbase + (4 * c + (g >> 1)) * 64 + (g & 1) * 4;
            vb[c][dt] = u4v8(*(const uint2*)vp, *(const uint2*)(vp + 128));
        }

    const v4f zf = {0.f, 0.f, 0.f, 0.f};
    v4f s[4];
    #pragma unroll
    for (int kt = 0; kt < 4; kt++)
        s[kt] = __builtin_amdgcn_mfma_f32_16x16x32_bf16(ka[kt], qf, zf, 0, 0, 0);

    float lsum = 0.f;
    uint2 u0, u1, u2, u3;
    {
        v4f sc;
        #pragma unroll
        for (int r = 0; r < 4; r++) sc[r] = s[0][r] * SCL2;
        u0 = expack2(sc, lsum);
        #pragma unroll
        for (int r = 0; r < 4; r++) sc[r] = s[1][r] * SCL2;
        u1 = expack2(sc, lsum);
        #pragma unroll
        for (int r = 0; r < 4; r++) sc[r] = s[2][r] * SCL2;
        u2 = expack2(sc, lsum);
        #pragma unroll
        for (int r = 0; r < 4; r++) sc[r] = s[3][r] * SCL2;
        u3 = expack2(sc, lsum);
    }
    lsum += __shfl_xor(lsum, 16);
    lsum += __shfl_xor(lsum, 32);
    float inv = 1.f / lsum;

    v8s pa0 = u4v8(u0, u1), pa1 = u4v8(u2, u3);
    v4f o0 = zf, o1 = zf;
    o0 = __builtin_amdgcn_mfma_f32_16x16x32_bf16(pa0, vb[0][0], o0, 0, 0, 0);
    o1 = __builtin_amdgcn_mfma_f32_16x16x32_bf16(pa0, vb[0][1], o1, 0, 0, 0);
    o0 = __builtin_amdgcn_mfma_f32_16x16x32_bf16(pa1, vb[1][0], o0, 0, 0, 0);
    o1 = __builtin_amdgcn_mfma_f32_16x16x32_bf16(pa1, vb[1][1], o1, 0, 0, 0);

    float invq[4];
    #pragma unroll
    for (int r = 0; r < 4; r++) invq[r] = __shfl(inv, g * 4 + r);

    int t0 = w * 16 + g * 4;
    int px0 = rowbase + (t0 >> 3) * 64 + (t0 & 7);
    unsigned short* op0 = gxb + ((size_t)b * 256 + h * 32 + m) * 4096 + px0;
    *(uint2*)op0 = make_uint2(pack2(o0[0] * invq[0], o0[1] * invq[1]),
                              pack2(o0[2] * invq[2], o0[3] * invq[3]));
    unsigned short* op1 = gxb + ((size_t)b * 256 + h * 32 + 16 + m) * 4096 + px0;
    *(uint2*)op1 = make_uint2(pack2(o1[0] * invq[0], o1[1] * invq[1]),
                              pack2(o1[2] * invq[2], o1[3] * invq[3]));
}

// ---------------- patch-merge layernorm (reads coalesced gxT, writes bf16 mn) ----------
__global__ __launch_bounds__(256) void patch_merge_ln2(
    const unsigned short* __restrict__ gxT,
    const float* __restrict__ lnw, const float* __restrict__ lnb,
    unsigned short* __restrict__ mn)
{
    int pix = blockIdx.x;
    int b = pix >> 10, op = pix & 1023;
    int oh = op >> 5, ow = op & 31;
    int t = threadIdx.x;
    const unsigned short* base = gxT + (size_t)b * 4096 * 256;
    float v[4];
    #pragma unroll
    for (int i = 0; i < 4; i++) {
        int h = 2 * oh + (i & 1);
        int w = 2 * ow + (i >> 1);
        v[i] = bf2f(base[(size_t)(h * 64 + w) * 256 + t]);
    }
    float s  = v[0] + v[1] + v[2] + v[3];
    float s2 = v[0]*v[0] + v[1]*v[1] + v[2]*v[2] + v[3]*v[3];
    __shared__ float ls[256], ls2[256];
    ls[t] = s; ls2[t] = s2; __syncthreads();
    for (int off = 128; off > 0; off >>= 1) {
        if (t < off) { ls[t] += ls[t + off]; ls2[t] += ls2[t + off]; }
        __syncthreads();
    }
    float mu  = ls[0] * (1.f / 1024.f);
    float var = ls2[0] * (1.f / 1024.f) - mu * mu;
    float r = rsqrtf(var + EPS_LN);
    unsigned short* orow = mn + (size_t)pix * 1024;
    #pragma unroll
    for (int i = 0; i < 4; i++) {
        int j = i * 256 + t;
        orow[j] = f2bf((v[i] - mu) * r * lnw[j] + lnb[j]);
    }
}

// ---------------- global attention: 4 Q-frags/wave, pinned prefetch, fused epilogue -----
// qT: [B*8][4096][32] bf16 (SCALE*log2e folded); kT: [B*8][1024][32]; vT: [B*8][32][1024]
// (vperm'd key positions). Reads gxT, writes projT = bf16(gxT + O) p-major.
__global__ __launch_bounds__(256, 2) void global_attn_mfma(
    const unsigned short* __restrict__ qT,
    const unsigned short* __restrict__ kT,
    const unsigned short* __restrict__ vT,
    const unsigned short* __restrict__ gxT,
    unsigned short* __restrict__ projT)
{
    int blk = blockIdx.x;               // b*128 + h*16 + qt  (512 blocks)
    int qt = blk & 15, h = (blk >> 4) & 7, b = blk >> 7;
    int bh = b * 8 + h;
    int w = threadIdx.x >> 6, lane = threadIdx.x & 63;
    int m = lane & 15, g = lane >> 4;
    int qbase = qt * 256 + w * 64;

    const unsigned short* qp = qT + ((size_t)bh * 4096 + qbase + m) * 32 + g * 8;
    v8s qf0 = *(const v8s*)(qp);
    v8s qf1 = *(const v8s*)(qp + 16 * 32);
    v8s qf2 = *(const v8s*)(qp + 32 * 32);
    v8s qf3 = *(const v8s*)(qp + 48 * 32);

    const v4f zf = {0.f, 0.f, 0.f, 0.f};
    v4f o00 = zf, o01 = zf, o10 = zf, o11 = zf;
    v4f o20 = zf, o21 = zf, o30 = zf, o31 = zf;
    float l0 = 0.f, l1 = 0.f, l2 = 0.f, l3 = 0.f;

    const unsigned short* kbase = kT + ((size_t)bh * 1024 + m) * 32 + g * 8;
    const unsigned short* vbase = vT + ((size_t)bh * 32 + m) * 1024 + g * 8;

    // prologue: tile 0 into current regs
    v8s ka0 = *(const v8s*)(kbase);
    v8s ka1 = *(const v8s*)(kbase + 16 * 32);
    v8s ka2 = *(const v8s*)(kbase + 32 * 32);
    v8s ka3 = *(const v8s*)(kbase + 48 * 32);
    v8s vb0 = *(const v8s*)(vbase);
    v8s vb1 = *(const v8s*)(vbase + 16 * 1024);
    v8s vb2 = *(const v8s*)(vbase + 32);
    v8s vb3 = *(const v8s*)(vbase + 32 + 16 * 1024);

    #pragma unroll 2
    for (int t = 0; t < 16; t++) {
        // prefetch tile t+1 (last iter re-loads tile 15; harmless)
        int kn = (t < 15 ? t + 1 : 15) * 64;
        const unsigned short* kp = kbase + (size_t)kn * 32;
        const unsigned short* vp = vbase + kn;
        v8s nk0 = *(const v8s*)(kp);
        v8s nk1 = *(const v8s*)(kp + 16 * 32);
        v8s nk2 = *(const v8s*)(kp + 32 * 32);
        v8s nk3 = *(const v8s*)(kp + 48 * 32);
        v8s nv0 = *(const v8s*)(vp);
        v8s nv1 = *(const v8s*)(vp + 16 * 1024);
        v8s nv2 = *(const v8s*)(vp + 32);
        v8s nv3 = *(const v8s*)(vp + 32 + 16 * 1024);
        // pin: prefetch loads must be issued before the compute below
        __builtin_amdgcn_sched_barrier(0);

        // qi = 0
        {
            v4f s0 = __builtin_amdgcn_mfma_f32_16x16x32_bf16(ka0, qf0, zf, 0, 0, 0);
            v4f s1 = __builtin_amdgcn_mfma_f32_16x16x32_bf16(ka1, qf0, zf, 0, 0, 0);
            v4f s2 = __builtin_amdgcn_mfma_f32_16x16x32_bf16(ka2, qf0, zf, 0, 0, 0);
            v4f s3 = __builtin_amdgcn_mfma_f32_16x16x32_bf16(ka3, qf0, zf, 0, 0, 0);
            uint2 a0 = expack2(s0, l0), a1 = expack2(s1, l0);
            uint2 a2 = expack2(s2, l0), a3 = expack2(s3, l0);
            v8s pa0 = u4v8(a0, a1), pa1 = u4v8(a2, a3);
            o00 = __builtin_amdgcn_mfma_f32_16x16x32_bf16(pa0, vb0, o00, 0, 0, 0);
            o01 = __builtin_amdgcn_mfma_f32_16x16x32_bf16(pa0, vb1, o01, 0, 0, 0);
            o00 = __builtin_amdgcn_mfma_f32_16x16x32_bf16(pa1, vb2, o00, 0, 0, 0);
            o01 = __builtin_amdgcn_mfma_f32_16x16x32_bf16(pa1, vb3, o01, 0, 0, 0);
        }
        // qi = 1
        {
            v4f s0 = __builtin_amdgcn_mfma_f32_16x16x32_bf16(ka0, qf1, zf, 0, 0, 0);
            v4f s1 = __builtin_amdgcn_mfma_f32_16x16x32_bf16(ka1, qf1, zf, 0, 0, 0);
            v4f s2 = __builtin_amdgcn_mfma_f32_16x16x32_bf16(ka2, qf1, zf, 0, 0, 0);
            v4f s3 = __builtin_amdgcn_mfma_f32_16x16x32_bf16(ka3, qf1, zf, 0, 0, 0);
            uint2 a0 = expack2(s0, l1), a1 = expack2(s1, l1);
            uint2 a2 = expack2(s2, l1), a3 = expack2(s3, l1);
            v8s pa0 = u4v8(a0, a1), pa1 = u4v8(a2, a3);
            o10 = __builtin_amdgcn_mfma_f32_16x16x32_bf16(pa0, vb0, o10, 0, 0, 0);
            o11 = __builtin_amdgcn_mfma_f32_16x16x32_bf16(pa0, vb1, o11, 0, 0, 0);
            o10 = __builtin_amdgcn_mfma_f32_16x16x32_bf16(pa1, vb2, o10, 0, 0, 0);
            o11 = __builtin_amdgcn_mfma_f32_16x16x32_bf16(pa1, vb3, o11, 0, 0, 0);
        }
        // qi = 2
        {
            v4f s0 = __builtin_amdgcn_mfma_f32_16x16x32_bf16(ka0, qf2, zf, 0, 0, 0);
            v4f s1 = __builtin_amdgcn_mfma_f32_16x16x32_bf16(ka1, qf2, zf, 0, 0, 0);
            v4f s2 = __builtin_amdgcn_mfma_f32_16x16x32_bf16(ka2, qf2, zf, 0, 0, 0);
            v4f s3 = __builtin_amdgcn_mfma_f32_16x16x32_bf16(ka3, qf2, zf, 0, 0, 0);
            uint2 a0 = expack2(s0, l2), a1 = expack2(s1, l2);
            uint2 a2 = expack2(s2, l2), a3 = expack2(s3, l2);
            v8s pa0 = u4v8(a0, a1), pa1 = u4v8(a2, a3);
            o20 = __builtin_amdgcn_mfma_f32_16x16x32_bf16(pa0, vb0, o20, 0, 0, 0);
            o21 = __builtin_amdgcn_mfma_f32_16x16x32_bf16(pa0, vb1, o21, 0, 0, 0);
            o20 = __builtin_amdgcn_mfma_f32_16x16x32_bf16(pa1, vb2, o20, 0, 0, 0);
            o21 = __builtin_amdgcn_mfma_f32_16x16x32_bf16(pa1, vb3, o21, 0, 0, 0);
        }
        // qi = 3
        {
            v4f s0 = __builtin_amdgcn_mfma_f32_16x16x32_bf16(ka0, qf3, zf, 0, 0, 0);
            v4f s1 = __builtin_amdgcn_mfma_f32_16x16x32_bf16(ka1, qf3, zf, 0, 0, 0);
            v4f s2 = __builtin_amdgcn_mfma_f32_16x16x32_bf16(ka2, qf3, zf, 0, 0, 0);
            v4f s3 = __builtin_amdgcn_mfma_f32_16x16x32_bf16(ka3, qf3, zf, 0, 0, 0);
            uint2 a0 = expack2(s0, l3), a1 = expack2(s1, l3);
            uint2 a2 = expack2(s2, l3), a3 = expack2(s3, l3);
            v8s pa0 = u4v8(a0, a1), pa1 = u4v8(a2, a3);
            o30 = __builtin_amdgcn_mfma_f32_16x16x32_bf16(pa0, vb0, o30, 0, 0, 0);
            o31 = __builtin_amdgcn_mfma_f32_16x16x32_bf16(pa0, vb1, o31, 0, 0, 0);
            o30 = __builtin_amdgcn_mfma_f32_16x16x32_bf16(pa1, vb2, o30, 0, 0, 0);
            o31 = __builtin_amdgcn_mfma_f32_16x16x32_bf16(pa1, vb3, o31, 0, 0, 0);
        }

        ka0 = nk0; ka1 = nk1; ka2 = nk2; ka3 = nk3;
        vb0 = nv0; vb1 = nv1; vb2 = nv2; vb3 = nv3;
    }

    float lf[4] = {l0, l1, l2, l3};
    v4f oq0[4] = {o00, o10, o20, o30};
    v4f oq1[4] = {o01, o11, o21, o31};
    #pragma unroll
    for (int qi = 0; qi < 4; qi++) {
        float lfq = lf[qi];
        lfq += __shfl_xor(lfq, 16);
        lfq += __shfl_xor(lfq, 32);
        float inv = 1.f / lfq;
        float invq[4];
        #pragma unroll
        for (int r = 0; r < 4; r++) invq[r] = __shfl(inv, g * 4 + r);
        #pragma unroll
        for (int r = 0; r < 4; r++) {
            size_t row = ((size_t)b * 4096 + qbase + qi * 16 + g * 4 + r) * 256 + h * 32;
            projT[row + m]      = f2bf(bf2f(gxT[row + m])      + oq0[qi][r] * invq[r]);
            projT[row + 16 + m] = f2bf(bf2f(gxT[row + 16 + m]) + oq1[qi][r] * invq[r]);
        }
    }
}

// ---------------- launcher ----------------
extern "C" void kernel_launch(void* const* d_in, const int* in_sizes, int n_in,
                              void* d_out, int out_size, void* d_ws, size_t ws_size,
                              hipStream_t stream)
{
    const float* x           = (const float*)d_in[0];
    const float* norm_w      = (const float*)d_in[1];
    const float* norm_b      = (const float*)d_in[2];
    const float* qkv_w       = (const float*)d_in[3];
    const float* qkv_b       = (const float*)d_in[4];
    const float* proj_w      = (const float*)d_in[5];
    const float* proj_b      = (const float*)d_in[6];
    const float* grid_norm_w = (const float*)d_in[7];
    const float* grid_norm_b = (const float*)d_in[8];
    const float* pm_ln_w     = (const float*)d_in[9];
    const float* pm_ln_b     = (const float*)d_in[10];
    const float* pm_red_w    = (const float*)d_in[11];
    const float* ds_norm_w   = (const float*)d_in[12];
    const float* ds_norm_b   = (const float*)d_in[13];
    const float* q_w         = (const float*)d_in[14];
    const float* q_b         = (const float*)d_in[15];
    const float* kv_w        = (const float*)d_in[16];
    const float* kv_b        = (const float*)d_in[17];
    float* out = (float*)d_out;

    float* wsf = (float*)d_ws;
    unsigned short* qkp   = (unsigned short*)(wsf);
    unsigned short* vbb   = (unsigned short*)(wsf + 4194304);
    unsigned short* mnb   = (unsigned short*)(wsf);
    unsigned short* kTu   = (unsigned short*)(wsf);
    unsigned short* vTu   = (unsigned short*)(wsf + 524288);
    float* pm             = wsf + 2097152;
    unsigned short* pmT   = (unsigned short*)(wsf + 3145728);
    unsigned short* qTu   = (unsigned short*)(wsf + 10485760);
    unsigned short* gxb   = (unsigned short*)(wsf + 12582912);
    unsigned short* projT = (unsigned short*)(wsf + 12582912);  // gxb dead before step 12
    unsigned short* xT    = (unsigned short*)(wsf + 16777216);
    unsigned short* gxT   = (unsigned short*)(wsf + 16777216);
    float* part   = wsf + 18874368;
    unsigned short* wbf   = (unsigned short*)(wsf + 18875392);
    unsigned short* wbf_qkv  = wbf;
    unsigned short* wbf_pm   = wbf + 196608;
    unsigned short* wbf_kv   = wbf + 458752;
    unsigned short* wbf_q    = wbf + 589824;
    unsigned short* wbf_proj = wbf + 655360;

    // 1. weights -> bf16  +  partial stats of x (fused, independent block ranges)
    prep_kernel<<<960, 256, 0, stream>>>(qkv_w, pm_red_w, kv_w, q_w, proj_w, wbf, x, part);
    // 2. xT = bf16(GN(x)) p-major (stats finalized inline)
    tnc<<<dim3(64, 4, BATCH), 256, 0, stream>>>(
        x, nullptr, part, 64, 1.f / 1048576.f, EPS_GN, norm_w, norm_b, xT, 4096);
    // 3. qkv GEMM (MFMA 128x128) -> qkp + vbb
    gemm_bf16<1><<<dim3(32, 6, BATCH), 256, 0, stream>>>(
        xT, wbf_qkv, qkv_b, nullptr, qkp, vbb, nullptr, 256, 4096, 768, 1.f);
    // 4. local windowed attention (MFMA, LDS-free) -> gxb bf16 c-major
    local_attn_mfma<<<2048, 256, 0, stream>>>(qkp, vbb, gxb);
    // 5. partial stats of x+gx
    gn_partial4<<<BATCH * 64, 256, 0, stream>>>(x, gxb, 262144, 64, part);
    // 6. gxT = bf16(GN(x+gx)) p-major
    tnc<<<dim3(64, 4, BATCH), 256, 0, stream>>>(
        x, gxb, part, 64, 1.f / 1048576.f, EPS_GN, grid_norm_w, grid_norm_b, gxT, 4096);
    // 7. patch-merge LN -> mn bf16
    patch_merge_ln2<<<4096, 256, 0, stream>>>(gxT, pm_ln_w, pm_ln_b, mnb);
    // 8. patch-merge reduction GEMM (MFMA 128x128) + fused GN stage-1 partials
    gemm_bf16<0><<<dim3(8, 2, BATCH), 256, 0, stream>>>(
        mnb, wbf_pm, nullptr, pm, nullptr, nullptr, part, 1024, 1024, 256, 1.f);
    // 9. pmT = bf16(GN(pm)) p-major (nblk = 16 tiles/batch from step 8)
    tnc<<<dim3(16, 4, BATCH), 256, 0, stream>>>(
        pm, nullptr, part, 16, 1.f / 262144.f, EPS_GN, ds_norm_w, ds_norm_b, pmT, 1024);
    // 10. kv GEMM (MFMA 128x128) -> kTu (p-major) + vTu (c-major, vperm'd)
    gemm_bf16<3><<<dim3(8, 4, BATCH), 256, 0, stream>>>(
        pmT, wbf_kv, kv_b, nullptr, kTu, vTu, nullptr, 256, 1024, 512, 1.f);
    // 11. q GEMM (MFMA 128x128) -> qTu (head-split p-major, SCALE*log2e folded)
    gemm_bf16<2><<<dim3(32, 2, BATCH), 256, 0, stream>>>(
        gxT, wbf_q, q_b, nullptr, qTu, nullptr, nullptr, 256, 4096, 256, SCL2);
    // 12. global attention (MFMA, 4 Q-frags/wave, pinned prefetch) -> projT = bf16(gxT + O)
    global_attn_mfma<<<512, 256, 0, stream>>>(qTu, kTu, vTu, gxT, projT);
    // 13. proj GEMM (MFMA 128x128) -> out
    gemm_bf16<0><<<dim3(32, 2, BATCH), 256, 0, stream>>>(
        projT, wbf_proj, proj_b, out, nullptr, nullptr, nullptr, 256, 4096, 256, 1.f);
}

// Round 18
// 155.212 us; speedup vs baseline: 1.6050x; 1.0053x over previous
//
#include <hip/hip_runtime.h>
#include <hip/hip_bf16.h>

// Problem constants
#define BATCH 4
#define CDIM 256
#define HWSZ 4096          // 64*64
#define P2 1024            // 32*32 pooled pixels per batch
#define SCALE 0.17677669529663687f
#define LOG2E 1.4426950408889634f
#define SCL2 (SCALE * LOG2E)
#define EPS_GN 1e-6f
#define EPS_LN 1e-5f
#define MFIX 8.0f          // fixed softmax shift (scores are O(1); exp(s-8) can't overflow)
#define MFIX2 (MFIX * LOG2E)

typedef short v8s __attribute__((ext_vector_type(8)));
typedef float v4f __attribute__((ext_vector_type(4)));

__device__ __forceinline__ unsigned short f2bf(float f) {
    __hip_bfloat16 h = __float2bfloat16(f);
    return *reinterpret_cast<unsigned short*>(&h);
}
__device__ __forceinline__ float bf2f(unsigned short u) {
    return __uint_as_float(((unsigned int)u) << 16);
}
__device__ __forceinline__ float bflo(unsigned int u) {
    return __uint_as_float(u << 16);
}
__device__ __forceinline__ float bfhi(unsigned int u) {
    return __uint_as_float(u & 0xffff0000u);
}
__device__ __forceinline__ unsigned int pack2(float lo, float hi) {
    return (unsigned int)f2bf(lo) | ((unsigned int)f2bf(hi) << 16);
}
// truncating bf16 pack (P-values only: softmax ratio cancels the truncation bias)
__device__ __forceinline__ unsigned int tpack2(float lo, float hi) {
    return (__float_as_uint(lo) >> 16) | (__float_as_uint(hi) & 0xffff0000u);
}
__device__ __forceinline__ float fexp2(float x) {
#if __has_builtin(__builtin_amdgcn_exp2f)
    return __builtin_amdgcn_exp2f(x);
#else
    return exp2f(x);
#endif
}
// 2^(s-MFIX2) for 4 log2-domain scores -> packed 4xbf16 (truncated), accumulating sum
__device__ __forceinline__ uint2 expack2(v4f s, float& sum) {
    float a = fexp2(s[0] - MFIX2);
    float b = fexp2(s[1] - MFIX2);
    float c = fexp2(s[2] - MFIX2);
    float d = fexp2(s[3] - MFIX2);
    sum += (a + b) + (c + d);
    return make_uint2(tpack2(a, b), tpack2(c, d));
}
__device__ __forceinline__ v8s u4v8(uint2 a, uint2 b) {
    union { unsigned int u[4]; v8s v; } r;
    r.u[0] = a.x; r.u[1] = a.y; r.u[2] = b.x; r.u[3] = b.y;
    return r.v;
}
// V key permutation within a 64-key block: S^T reg order -> PV A-frag contract order.
__device__ __forceinline__ int vperm(int j) {
    return (j & 0x23) | ((j & 0x0C) << 1) | ((j & 0x10) >> 2);
}
__device__ __forceinline__ void async16(void* lds, const void* g) {
    __builtin_amdgcn_global_load_lds(
        (const __attribute__((address_space(1))) unsigned int*)g,
        (__attribute__((address_space(3))) unsigned int*)lds, 16, 0, 0);
}

// ------- prep: weight cast (blocks 0..703) + GN partial stats of x (blocks 704..959) ----
__global__ void prep_kernel(const float* __restrict__ w0, const float* __restrict__ w1,
                            const float* __restrict__ w2, const float* __restrict__ w3,
                            const float* __restrict__ w4, unsigned short* __restrict__ dst,
                            const float* __restrict__ x, float* __restrict__ part)
{
    int bid = blockIdx.x;
    int tid = threadIdx.x;
    if (bid < 704) {
        int idx = (bid * 256 + tid) * 4;
        const float* src; int off;
        if      (idx < 196608) { src = w0; off = 0; }
        else if (idx < 458752) { src = w1; off = 196608; }
        else if (idx < 589824) { src = w2; off = 458752; }
        else if (idx < 655360) { src = w3; off = 589824; }
        else                   { src = w4; off = 655360; }
        float4 v = *(const float4*)(src + idx - off);
        *(uint2*)(dst + idx) = make_uint2(pack2(v.x, v.y), pack2(v.z, v.w));
        return;
    }
    // x stats: 256 blocks, nblk=64 per batch, pb4=262144
    int blk2 = bid - 704;
    int bb = blk2 >> 6, blk = blk2 & 63;
    const float* pa = x + (size_t)bb * 1048576;
    float s = 0.f, s2 = 0.f;
    for (int i = blk * 256 + tid; i < 262144; i += 64 * 256) {
        float4 v = *(const float4*)(pa + (size_t)i * 4);
        s += (v.x + v.y) + (v.z + v.w);
        s2 += fmaf(v.x, v.x, fmaf(v.y, v.y, fmaf(v.z, v.z, v.w * v.w)));
    }
    __shared__ float ls[256], ls2[256];
    ls[tid] = s; ls2[tid] = s2; __syncthreads();
    for (int off = 128; off > 0; off >>= 1) {
        if (tid < off) { ls[tid] += ls[tid + off]; ls2[tid] += ls2[tid + off]; }
        __syncthreads();
    }
    if (tid == 0) {
        part[blk2 * 2]     = ls[0];
        part[blk2 * 2 + 1] = ls2[0];
    }
}

// ---------------- GroupNorm partial stats (fp32 a + optional bf16 addend) ----------
__global__ void gn_partial4(const float* __restrict__ a, const unsigned short* __restrict__ a2bf,
                            int pb4, int nblk, float* __restrict__ part)
{
    int bb  = blockIdx.x / nblk;
    int blk = blockIdx.x % nblk;
    const float* pa = a + (size_t)bb * pb4 * 4;
    const unsigned short* pa2 = a2bf ? a2bf + (size_t)bb * pb4 * 4 : nullptr;
    int tid = threadIdx.x;
    float s = 0.f, s2 = 0.f;
    for (int i = blk * 256 + tid; i < pb4; i += nblk * 256) {
        float4 v = *(const float4*)(pa + (size_t)i * 4);
        if (pa2) {
            uint2 g = *(const uint2*)(pa2 + (size_t)i * 4);
            v.x += bflo(g.x); v.y += bfhi(g.x);
            v.z += bflo(g.y); v.w += bfhi(g.y);
        }
        s += (v.x + v.y) + (v.z + v.w);
        s2 += fmaf(v.x, v.x, fmaf(v.y, v.y, fmaf(v.z, v.z, v.w * v.w)));
    }
    __shared__ float ls[256], ls2[256];
    ls[tid] = s; ls2[tid] = s2; __syncthreads();
    for (int off = 128; off > 0; off >>= 1) {
        if (tid < off) { ls[tid] += ls[tid + off]; ls2[tid] += ls2[tid + off]; }
        __syncthreads();
    }
    if (tid == 0) {
        part[blockIdx.x * 2]     = ls[0];
        part[blockIdx.x * 2 + 1] = ls2[0];
    }
}

// ------- transpose + (optional bf16 add) + norm (stats finalized inline) + cast ---------
// A: [b][256][P] fp32 c-major.  A2b: optional bf16 addend same layout.  dst: [b][P][256] bf16.
__global__ __launch_bounds__(256) void tnc(
    const float* __restrict__ A, const unsigned short* __restrict__ A2b,
    const float* __restrict__ part, int nblk, float inv_n, float eps,
    const float* __restrict__ nw, const float* __restrict__ nb,
    unsigned short* __restrict__ dst, int P)
{
    int b = blockIdx.z, c0 = blockIdx.y * 64, p0 = blockIdx.x * 64;
    __shared__ float ld[64][65];
    __shared__ float sstat[2];
    int t = threadIdx.x;
    if (t < 64) {
        float s = 0.f, s2 = 0.f;
        if (t < nblk) {
            s  = part[(b * nblk + t) * 2];
            s2 = part[(b * nblk + t) * 2 + 1];
        }
        #pragma unroll
        for (int off = 32; off > 0; off >>= 1) {
            s  += __shfl_down(s, off);
            s2 += __shfl_down(s2, off);
        }
        if (t == 0) {
            float mval = s * inv_n;
            float var  = s2 * inv_n - mval * mval;
            sstat[0] = mval;
            sstat[1] = rsqrtf(var + eps);
        }
    }
    __syncthreads();
    float mean = sstat[0], rstd = sstat[1];
    {
        int ch = t >> 2, pq = (t & 3) * 16;
        size_t base = ((size_t)b * 256 + c0 + ch) * P + p0 + pq;
        float4 f0 = *(const float4*)(A + base);
        float4 f1 = *(const float4*)(A + base + 4);
        float4 f2 = *(const float4*)(A + base + 8);
        float4 f3 = *(const float4*)(A + base + 12);
        if (A2b) {
            const unsigned short* ap = A2b + base;
            uint4 q0 = *(const uint4*)(ap);
            uint4 q1 = *(const uint4*)(ap + 8);
            f0.x += bflo(q0.x); f0.y += bfhi(q0.x); f0.z += bflo(q0.y); f0.w += bfhi(q0.y);
            f1.x += bflo(q0.z); f1.y += bfhi(q0.z); f1.z += bflo(q0.w); f1.w += bfhi(q0.w);
            f2.x += bflo(q1.x); f2.y += bfhi(q1.x); f2.z += bflo(q1.y); f2.w += bfhi(q1.y);
            f3.x += bflo(q1.z); f3.y += bfhi(q1.z); f3.z += bflo(q1.w); f3.w += bfhi(q1.w);
        }
        float wv = nw[c0 + ch];
        float sw = rstd * wv;
        float sb = nb[c0 + ch] - mean * rstd * wv;
        ld[ch][pq + 0]  = f0.x * sw + sb; ld[ch][pq + 1]  = f0.y * sw + sb;
        ld[ch][pq + 2]  = f0.z * sw + sb; ld[ch][pq + 3]  = f0.w * sw + sb;
        ld[ch][pq + 4]  = f1.x * sw + sb; ld[ch][pq + 5]  = f1.y * sw + sb;
        ld[ch][pq + 6]  = f1.z * sw + sb; ld[ch][pq + 7]  = f1.w * sw + sb;
        ld[ch][pq + 8]  = f2.x * sw + sb; ld[ch][pq + 9]  = f2.y * sw + sb;
        ld[ch][pq + 10] = f2.z * sw + sb; ld[ch][pq + 11] = f2.w * sw + sb;
        ld[ch][pq + 12] = f3.x * sw + sb; ld[ch][pq + 13] = f3.y * sw + sb;
        ld[ch][pq + 14] = f3.z * sw + sb; ld[ch][pq + 15] = f3.w * sw + sb;
    }
    __syncthreads();
    {
        int p = t >> 2, cb = (t & 3) * 16;
        unsigned int u[8];
        #pragma unroll
        for (int j = 0; j < 8; j++)
            u[j] = pack2(ld[cb + 2 * j][p], ld[cb + 2 * j + 1][p]);
        unsigned short* dp = dst + ((size_t)b * P + p0 + p) * 256 + c0 + cb;
        *(uint4*)(dp)     = make_uint4(u[0], u[1], u[2], u[3]);
        *(uint4*)(dp + 8) = make_uint4(u[4], u[5], u[6], u[7]);
    }
}

// ---------------- MFMA GEMM (128x128 tile): OUT = actT * W^T + bias ----------
// MODE 0: OUT fp32 c-major [B][OC][P]; optional partOut: per-block (sum,sumsq) partials.
// MODE 1: qkv split -> aux1 = qkp bf16 [B][4096][512] p-major (ch<512);
//         ch>=512 (V) -> aux2 bf16 c-major [B][256][4096].
// MODE 3: kv: ch<256 (K) -> aux1 [B*8][1024][32] p-major; ch>=256 (V) -> aux2 [B*8][32][1024]
//         c-major with vperm'd key positions.
template<int MODE>
__global__ __launch_bounds__(256, 3) void gemm_bf16(
    const unsigned short* __restrict__ actT,
    const unsigned short* __restrict__ Wb,
    const float* __restrict__ bias,
    float* __restrict__ out,
    unsigned short* __restrict__ aux1,
    unsigned short* __restrict__ aux2,
    float* __restrict__ partOut,
    int K, int P, int OC, float oscale)
{
    int b  = blockIdx.z;
    int p0 = blockIdx.x * 128;
    int m0 = blockIdx.y * 128;
    int tid = threadIdx.x;
    int w = tid >> 6, lane = tid & 63;
    int lm = lane & 15, lg = lane >> 4;
    int wm = w >> 1, wp = w & 1;
    int l8 = lane >> 3, cc = lane & 7;

    __shared__ __align__(16) unsigned short Wt[128 * 64];   // [m][64k], swizzled
    __shared__ __align__(16) unsigned short At[128 * 64];   // [p][64k], swizzled

    const unsigned short* actB = actT + (size_t)b * P * K;

    v4f acc[4][4];
    #pragma unroll
    for (int i = 0; i < 4; i++)
        #pragma unroll
        for (int j = 0; j < 4; j++) acc[i][j] = (v4f){0.f, 0.f, 0.f, 0.f};

    for (int ks = 0; ks < K; ks += 64) {
        #pragma unroll
        for (int i = 0; i < 4; i++) {
            int ml = w * 32 + i * 8 + l8;
            int g = cc ^ (ml & 7);
            async16(&Wt[ml * 64], Wb + (size_t)(m0 + ml) * K + ks + g * 8);
        }
        #pragma unroll
        for (int i = 0; i < 4; i++) {
            int pl = w * 32 + i * 8 + l8;
            int g = cc ^ (pl & 7);
            async16(&At[pl * 64], actB + (size_t)(p0 + pl) * K + ks + g * 8);
        }
        __syncthreads();
        #pragma unroll
        for (int kk = 0; kk < 2; kk++) {
            v8s af[4], bfv[4];
            #pragma unroll
            for (int mt = 0; mt < 4; mt++) {
                int m = wm * 64 + mt * 16 + lm;
                int ch = (kk * 4 + lg) ^ (m & 7);
                af[mt] = *(const v8s*)&Wt[m * 64 + ch * 8];
            }
            #pragma unroll
            for (int pt = 0; pt < 4; pt++) {
                int p = wp * 64 + pt * 16 + lm;
                int ch = (kk * 4 + lg) ^ (p & 7);
                bfv[pt] = *(const v8s*)&At[p * 64 + ch * 8];
            }
            #pragma unroll
            for (int mt = 0; mt < 4; mt++)
                #pragma unroll
                for (int pt = 0; pt < 4; pt++)
                    acc[mt][pt] = __builtin_amdgcn_mfma_f32_16x16x32_bf16(
                        af[mt], bfv[pt], acc[mt][pt], 0, 0, 0);
        }
        __syncthreads();
    }

    if constexpr (MODE == 1) {
        if (m0 < 512) {
            #pragma unroll
            for (int mt = 0; mt < 4; mt++) {
                int mch = m0 + wm * 64 + mt * 16 + lg * 4;
                float4 bs = *(const float4*)(bias + mch);
                #pragma unroll
                for (int pt = 0; pt < 4; pt++) {
                    int p = p0 + wp * 64 + pt * 16 + lm;
                    unsigned int u0 = pack2(acc[mt][pt][0] + bs.x, acc[mt][pt][1] + bs.y);
                    unsigned int u1 = pack2(acc[mt][pt][2] + bs.z, acc[mt][pt][3] + bs.w);
                    *(uint2*)(aux1 + ((size_t)(b * 4096 + p) * 512 + mch)) = make_uint2(u0, u1);
                }
            }
        } else {
            // V -> bf16 c-major [b][256][4096]
            #pragma unroll
            for (int mt = 0; mt < 4; mt++) {
                #pragma unroll
                for (int r = 0; r < 4; r++) {
                    int mch = m0 + wm * 64 + mt * 16 + lg * 4 + r;
                    float bsv = bias[mch];
                    unsigned short* orow = aux2 + ((size_t)b * 256 + (mch - 512)) * 4096
                                           + p0 + wp * 64;
                    #pragma unroll
                    for (int pt = 0; pt < 4; pt++)
                        orow[pt * 16 + lm] = f2bf(acc[mt][pt][r] + bsv);
                }
            }
        }
    } else if constexpr (MODE == 3) {
        #pragma unroll
        for (int mt = 0; mt < 4; mt++) {
            int ch = m0 + wm * 64 + mt * 16 + lg * 4;
            if (ch < 256) {     // K -> p-major [bh][1024][32]
                int head = ch >> 5, d = ch & 31;
                float4 bs = *(const float4*)(bias + ch);
                #pragma unroll
                for (int pt = 0; pt < 4; pt++) {
                    int p = p0 + wp * 64 + pt * 16 + lm;
                    unsigned int u0 = pack2(acc[mt][pt][0] + bs.x, acc[mt][pt][1] + bs.y);
                    unsigned int u1 = pack2(acc[mt][pt][2] + bs.z, acc[mt][pt][3] + bs.w);
                    *(uint2*)(aux1 + ((size_t)(b * 8 + head) * P + p) * 32 + d) = make_uint2(u0, u1);
                }
            } else {            // V -> c-major [bh][32][1024], vperm'd positions
                int v = ch - 256;
                int head = v >> 5, d0 = v & 31;
                #pragma unroll
                for (int pt = 0; pt < 4; pt++) {
                    int p = p0 + wp * 64 + pt * 16 + lm;
                    int pos = (p & ~63) | vperm(p & 63);
                    #pragma unroll
                    for (int r = 0; r < 4; r++)
                        aux2[((size_t)(b * 8 + head) * 32 + d0 + r) * P + pos] =
                            f2bf(acc[mt][pt][r] + bias[ch + r]);
                }
            }
        }
    } else {
        float s = 0.f, s2 = 0.f;
        #pragma unroll
        for (int mt = 0; mt < 4; mt++) {
            #pragma unroll
            for (int r = 0; r < 4; r++) {
                int m = m0 + wm * 64 + mt * 16 + lg * 4 + r;
                float bs = bias ? bias[m] : 0.f;
                float* orow = out + (size_t)b * OC * P + (size_t)m * P + p0 + wp * 64;
                #pragma unroll
                for (int pt = 0; pt < 4; pt++) {
                    float v = acc[mt][pt][r] + bs;
                    orow[pt * 16 + lm] = v;
                    s += v; s2 = fmaf(v, v, s2);
                }
            }
        }
        if (partOut) {
            __shared__ float rs[256], rs2[256];
            rs[tid] = s; rs2[tid] = s2; __syncthreads();
            for (int off = 128; off > 0; off >>= 1) {
                if (tid < off) { rs[tid] += rs[tid + off]; rs2[tid] += rs2[tid + off]; }
                __syncthreads();
            }
            if (tid == 0) {
                int tilesPB = gridDim.x * gridDim.y;
                int tile = blockIdx.y * gridDim.x + blockIdx.x;
                partOut[((size_t)b * tilesPB + tile) * 2]     = rs[0];
                partOut[((size_t)b * tilesPB + tile) * 2 + 1] = rs2[0];
            }
        }
    }
}

// ------ fused: q GEMM (blocks 0..255, MODE-2 style) + patch-merge LN (blocks 256..4351) --
// q GEMM: qTu[bh][p][32] bf16 = (gxT @ q_w^T + q_b) * SCL2, head-split p-major.
// pm LN : mn[b*1024+op][1024] bf16 layernorm rows from gxT.
__global__ __launch_bounds__(256, 3) void pmln_qgemm(
    const unsigned short* __restrict__ gxT,
    const unsigned short* __restrict__ Wb,   // wbf_q
    const float* __restrict__ bias,          // q_b
    unsigned short* __restrict__ qTu,
    const float* __restrict__ lnw, const float* __restrict__ lnb,
    unsigned short* __restrict__ mn,
    float oscale)
{
    __shared__ __align__(16) unsigned short Wt[128 * 64];
    __shared__ __align__(16) unsigned short At[128 * 64];
    __shared__ float ls[256], ls2[256];
    int tid = threadIdx.x;

    if (blockIdx.x < 256) {
        // ---- q GEMM body (K=256, P=4096, OC=256) ----
        int j = blockIdx.x;
        int p0 = (j & 31) * 128;
        int m0 = ((j >> 5) & 1) * 128;
        int b  = j >> 6;
        int w = tid >> 6, lane = tid & 63;
        int lm = lane & 15, lg = lane >> 4;
        int wm = w >> 1, wp = w & 1;
        int l8 = lane >> 3, cc = lane & 7;
        const unsigned short* actB = gxT + (size_t)b * 4096 * 256;

        v4f acc[4][4];
        #pragma unroll
        for (int i = 0; i < 4; i++)
            #pragma unroll
            for (int jj = 0; jj < 4; jj++) acc[i][jj] = (v4f){0.f, 0.f, 0.f, 0.f};

        for (int ks = 0; ks < 256; ks += 64) {
            #pragma unroll
            for (int i = 0; i < 4; i++) {
                int ml = w * 32 + i * 8 + l8;
                int g = cc ^ (ml & 7);
                async16(&Wt[ml * 64], Wb + (size_t)(m0 + ml) * 256 + ks + g * 8);
            }
            #pragma unroll
            for (int i = 0; i < 4; i++) {
                int pl = w * 32 + i * 8 + l8;
                int g = cc ^ (pl & 7);
                async16(&At[pl * 64], actB + (size_t)(p0 + pl) * 256 + ks + g * 8);
            }
            __syncthreads();
            #pragma unroll
            for (int kk = 0; kk < 2; kk++) {
                v8s af[4], bfv[4];
                #pragma unroll
                for (int mt = 0; mt < 4; mt++) {
                    int m = wm * 64 + mt * 16 + lm;
                    int ch = (kk * 4 + lg) ^ (m & 7);
                    af[mt] = *(const v8s*)&Wt[m * 64 + ch * 8];
                }
                #pragma unroll
                for (int pt = 0; pt < 4; pt++) {
                    int p = wp * 64 + pt * 16 + lm;
                    int ch = (kk * 4 + lg) ^ (p & 7);
                    bfv[pt] = *(const v8s*)&At[p * 64 + ch * 8];
                }
                #pragma unroll
                for (int mt = 0; mt < 4; mt++)
                    #pragma unroll
                    for (int pt = 0; pt < 4; pt++)
                        acc[mt][pt] = __builtin_amdgcn_mfma_f32_16x16x32_bf16(
                            af[mt], bfv[pt], acc[mt][pt], 0, 0, 0);
            }
            __syncthreads();
        }
        #pragma unroll
        for (int mt = 0; mt < 4; mt++) {
            int ch = m0 + wm * 64 + mt * 16 + lg * 4;
            int head = ch >> 5, d = ch & 31;
            float4 bs = *(const float4*)(bias + ch);
            #pragma unroll
            for (int pt = 0; pt < 4; pt++) {
                int p = p0 + wp * 64 + pt * 16 + lm;
                unsigned int u0 = pack2((acc[mt][pt][0] + bs.x) * oscale,
                                        (acc[mt][pt][1] + bs.y) * oscale);
                unsigned int u1 = pack2((acc[mt][pt][2] + bs.z) * oscale,
                                        (acc[mt][pt][3] + bs.w) * oscale);
                *(uint2*)(qTu + ((size_t)(b * 8 + head) * 4096 + p) * 32 + d) = make_uint2(u0, u1);
            }
        }
        return;
    }

    // ---- patch-merge LN body ----
    int pix = blockIdx.x - 256;
    int b = pix >> 10, op = pix & 1023;
    int oh = op >> 5, ow = op & 31;
    int t = tid;
    const unsigned short* base = gxT + (size_t)b * 4096 * 256;
    float v[4];
    #pragma unroll
    for (int i = 0; i < 4; i++) {
        int h = 2 * oh + (i & 1);
        int w2 = 2 * ow + (i >> 1);
        v[i] = bf2f(base[(size_t)(h * 64 + w2) * 256 + t]);
    }
    float s  = v[0] + v[1] + v[2] + v[3];
    float s2 = v[0]*v[0] + v[1]*v[1] + v[2]*v[2] + v[3]*v[3];
    ls[t] = s; ls2[t] = s2; __syncthreads();
    for (int off = 128; off > 0; off >>= 1) {
        if (t < off) { ls[t] += ls[t + off]; ls2[t] += ls2[t + off]; }
        __syncthreads();
    }
    float mu  = ls[0] * (1.f / 1024.f);
    float var = ls2[0] * (1.f / 1024.f) - mu * mu;
    float r = rsqrtf(var + EPS_LN);
    unsigned short* orow = mn + (size_t)pix * 1024;
    #pragma unroll
    for (int i = 0; i < 4; i++) {
        int jj = i * 256 + t;
        orow[jj] = f2bf((v[i] - mu) * r * lnw[jj] + lnb[jj]);
    }
}

// ---------------- local windowed attention, bf16 MFMA, fixed-max, LDS-free ----------------
// qkp: [B][4096][512] bf16 (Q ch 0-255, K ch 256-511); vbb: [B][256][4096] bf16 c-major.
// gxb: [B][256][4096] bf16 c-major output.
__global__ __launch_bounds__(256, 4) void local_attn_mfma(
    const unsigned short* __restrict__ qkp,
    const unsigned short* __restrict__ vbb,
    unsigned short* __restrict__ gxb)
{
    int win = blockIdx.x;                  // b*512 + h*64 + gy*8 + gxc
    int gxc = win & 7, gy = (win >> 3) & 7, h = (win >> 6) & 7, b = win >> 9;
    int w = threadIdx.x >> 6, lane = threadIdx.x & 63;
    int m = lane & 15, g = lane >> 4;

    int rowbase = (gy * 8) * 64 + gxc * 8;   // pixel of window token 0
    const unsigned short* qkb = qkp + (size_t)b * 4096 * 512;
    const unsigned short* vbase = vbb + (size_t)b * 256 * 4096;

    int tq = w * 16 + m;
    int pq = rowbase + (tq >> 3) * 64 + (tq & 7);
    v8s qf = *(const v8s*)(qkb + (size_t)pq * 512 + h * 32 + g * 8);

    v8s ka[4];
    #pragma unroll
    for (int kt = 0; kt < 4; kt++) {
        int tk = kt * 16 + m;
        int pk = rowbase + (tk >> 3) * 64 + (tk & 7);
        ka[kt] = *(const v8s*)(qkb + (size_t)pk * 512 + 256 + h * 32 + g * 8);
    }
    v8s vb[2][2];
    #pragma unroll
    for (int c = 0; c < 2; c++)
        #pragma unroll
        for (int dt = 0; dt < 2; dt++) {
            const unsigned short* vp = vbase + (size_t)(h * 32 + dt * 16 + m) * 4096
                              + rowbase + (4 * c + (g >> 1)) * 64 + (g & 1) * 4;
            vb[c][dt] = u4v8(*(const uint2*)vp, *(const uint2*)(vp + 128));
        }

    const v4f zf = {0.f, 0.f, 0.f, 0.f};
    v4f s[4];
    #pragma unroll
    for (int kt = 0; kt < 4; kt++)
        s[kt] = __builtin_amdgcn_mfma_f32_16x16x32_bf16(ka[kt], qf, zf, 0, 0, 0);

    float lsum = 0.f;
    uint2 u0, u1, u2, u3;
    {
        v4f sc;
        #pragma unroll
        for (int r = 0; r < 4; r++) sc[r] = s[0][r] * SCL2;
        u0 = expack2(sc, lsum);
        #pragma unroll
        for (int r = 0; r < 4; r++) sc[r] = s[1][r] * SCL2;
        u1 = expack2(sc, lsum);
        #pragma unroll
        for (int r = 0; r < 4; r++) sc[r] = s[2][r] * SCL2;
        u2 = expack2(sc, lsum);
        #pragma unroll
        for (int r = 0; r < 4; r++) sc[r] = s[3][r] * SCL2;
        u3 = expack2(sc, lsum);
    }
    lsum += __shfl_xor(lsum, 16);
    lsum += __shfl_xor(lsum, 32);
    float inv = 1.f / lsum;

    v8s pa0 = u4v8(u0, u1), pa1 = u4v8(u2, u3);
    v4f o0 = zf, o1 = zf;
    o0 = __builtin_amdgcn_mfma_f32_16x16x32_bf16(pa0, vb[0][0], o0, 0, 0, 0);
    o1 = __builtin_amdgcn_mfma_f32_16x16x32_bf16(pa0, vb[0][1], o1, 0, 0, 0);
    o0 = __builtin_amdgcn_mfma_f32_16x16x32_bf16(pa1, vb[1][0], o0, 0, 0, 0);
    o1 = __builtin_amdgcn_mfma_f32_16x16x32_bf16(pa1, vb[1][1], o1, 0, 0, 0);

    float invq[4];
    #pragma unroll
    for (int r = 0; r < 4; r++) invq[r] = __shfl(inv, g * 4 + r);

    int t0 = w * 16 + g * 4;
    int px0 = rowbase + (t0 >> 3) * 64 + (t0 & 7);
    unsigned short* op0 = gxb + ((size_t)b * 256 + h * 32 + m) * 4096 + px0;
    *(uint2*)op0 = make_uint2(pack2(o0[0] * invq[0], o0[1] * invq[1]),
                              pack2(o0[2] * invq[2], o0[3] * invq[3]));
    unsigned short* op1 = gxb + ((size_t)b * 256 + h * 32 + 16 + m) * 4096 + px0;
    *(uint2*)op1 = make_uint2(pack2(o1[0] * invq[0], o1[1] * invq[1]),
                              pack2(o1[2] * invq[2], o1[3] * invq[3]));
}

// ---------------- global attention: 4 Q-frags/wave, pinned prefetch, fused epilogue -----
// qT: [B*8][4096][32] bf16 (SCALE*log2e folded); kT: [B*8][1024][32]; vT: [B*8][32][1024]
// (vperm'd key positions). Reads gxT, writes projT = bf16(gxT + O) p-major.
__global__ __launch_bounds__(256, 2) void global_attn_mfma(
    const unsigned short* __restrict__ qT,
    const unsigned short* __restrict__ kT,
    const unsigned short* __restrict__ vT,
    const unsigned short* __restrict__ gxT,
    unsigned short* __restrict__ projT)
{
    int blk = blockIdx.x;               // b*128 + h*16 + qt  (512 blocks)
    int qt = blk & 15, h = (blk >> 4) & 7, b = blk >> 7;
    int bh = b * 8 + h;
    int w = threadIdx.x >> 6, lane = threadIdx.x & 63;
    int m = lane & 15, g = lane >> 4;
    int qbase = qt * 256 + w * 64;

    const unsigned short* qp = qT + ((size_t)bh * 4096 + qbase + m) * 32 + g * 8;
    v8s qf0 = *(const v8s*)(qp);
    v8s qf1 = *(const v8s*)(qp + 16 * 32);
    v8s qf2 = *(const v8s*)(qp + 32 * 32);
    v8s qf3 = *(const v8s*)(qp + 48 * 32);

    const v4f zf = {0.f, 0.f, 0.f, 0.f};
    v4f o00 = zf, o01 = zf, o10 = zf, o11 = zf;
    v4f o20 = zf, o21 = zf, o30 = zf, o31 = zf;
    float l0 = 0.f, l1 = 0.f, l2 = 0.f, l3 = 0.f;

    const unsigned short* kbase = kT + ((size_t)bh * 1024 + m) * 32 + g * 8;
    const unsigned short* vbase = vT + ((size_t)bh * 32 + m) * 1024 + g * 8;

    // prologue: tile 0 into current regs
    v8s ka0 = *(const v8s*)(kbase);
    v8s ka1 = *(const v8s*)(kbase + 16 * 32);
    v8s ka2 = *(const v8s*)(kbase + 32 * 32);
    v8s ka3 = *(const v8s*)(kbase + 48 * 32);
    v8s vb0 = *(const v8s*)(vbase);
    v8s vb1 = *(const v8s*)(vbase + 16 * 1024);
    v8s vb2 = *(const v8s*)(vbase + 32);
    v8s vb3 = *(const v8s*)(vbase + 32 + 16 * 1024);

    #pragma unroll 2
    for (int t = 0; t < 16; t++) {
        // prefetch tile t+1 (last iter re-loads tile 15; harmless)
        int kn = (t < 15 ? t + 1 : 15) * 64;
        const unsigned short* kp = kbase + (size_t)kn * 32;
        const unsigned short* vp = vbase + kn;
        v8s nk0 = *(const v8s*)(kp);
        v8s nk1 = *(const v8s*)(kp + 16 * 32);
        v8s nk2 = *(const v8s*)(kp + 32 * 32);
        v8s nk3 = *(const v8s*)(kp + 48 * 32);
        v8s nv0 = *(const v8s*)(vp);
        v8s nv1 = *(const v8s*)(vp + 16 * 1024);
        v8s nv2 = *(const v8s*)(vp + 32);
        v8s nv3 = *(const v8s*)(vp + 32 + 16 * 1024);
        // pin: prefetch loads must be issued before the compute below
        __builtin_amdgcn_sched_barrier(0);

        // qi = 0
        {
            v4f s0 = __builtin_amdgcn_mfma_f32_16x16x32_bf16(ka0, qf0, zf, 0, 0, 0);
            v4f s1 = __builtin_amdgcn_mfma_f32_16x16x32_bf16(ka1, qf0, zf, 0, 0, 0);
            v4f s2 = __builtin_amdgcn_mfma_f32_16x16x32_bf16(ka2, qf0, zf, 0, 0, 0);
            v4f s3 = __builtin_amdgcn_mfma_f32_16x16x32_bf16(ka3, qf0, zf, 0, 0, 0);
            uint2 a0 = expack2(s0, l0), a1 = expack2(s1, l0);
            uint2 a2 = expack2(s2, l0), a3 = expack2(s3, l0);
            v8s pa0 = u4v8(a0, a1), pa1 = u4v8(a2, a3);
            o00 = __builtin_amdgcn_mfma_f32_16x16x32_bf16(pa0, vb0, o00, 0, 0, 0);
            o01 = __builtin_amdgcn_mfma_f32_16x16x32_bf16(pa0, vb1, o01, 0, 0, 0);
            o00 = __builtin_amdgcn_mfma_f32_16x16x32_bf16(pa1, vb2, o00, 0, 0, 0);
            o01 = __builtin_amdgcn_mfma_f32_16x16x32_bf16(pa1, vb3, o01, 0, 0, 0);
        }
        // qi = 1
        {
            v4f s0 = __builtin_amdgcn_mfma_f32_16x16x32_bf16(ka0, qf1, zf, 0, 0, 0);
            v4f s1 = __builtin_amdgcn_mfma_f32_16x16x32_bf16(ka1, qf1, zf, 0, 0, 0);
            v4f s2 = __builtin_amdgcn_mfma_f32_16x16x32_bf16(ka2, qf1, zf, 0, 0, 0);
            v4f s3 = __builtin_amdgcn_mfma_f32_16x16x32_bf16(ka3, qf1, zf, 0, 0, 0);
            uint2 a0 = expack2(s0, l1), a1 = expack2(s1, l1);
            uint2 a2 = expack2(s2, l1), a3 = expack2(s3, l1);
            v8s pa0 = u4v8(a0, a1), pa1 = u4v8(a2, a3);
            o10 = __builtin_amdgcn_mfma_f32_16x16x32_bf16(pa0, vb0, o10, 0, 0, 0);
            o11 = __builtin_amdgcn_mfma_f32_16x16x32_bf16(pa0, vb1, o11, 0, 0, 0);
            o10 = __builtin_amdgcn_mfma_f32_16x16x32_bf16(pa1, vb2, o10, 0, 0, 0);
            o11 = __builtin_amdgcn_mfma_f32_16x16x32_bf16(pa1, vb3, o11, 0, 0, 0);
        }
        // qi = 2
        {
            v4f s0 = __builtin_amdgcn_mfma_f32_16x16x32_bf16(ka0, qf2, zf, 0, 0, 0);
            v4f s1 = __builtin_amdgcn_mfma_f32_16x16x32_bf16(ka1, qf2, zf, 0, 0, 0);
            v4f s2 = __builtin_amdgcn_mfma_f32_16x16x32_bf16(ka2, qf2, zf, 0, 0, 0);
            v4f s3 = __builtin_amdgcn_mfma_f32_16x16x32_bf16(ka3, qf2, zf, 0, 0, 0);
            uint2 a0 = expack2(s0, l2), a1 = expack2(s1, l2);
            uint2 a2 = expack2(s2, l2), a3 = expack2(s3, l2);
            v8s pa0 = u4v8(a0, a1), pa1 = u4v8(a2, a3);
            o20 = __builtin_amdgcn_mfma_f32_16x16x32_bf16(pa0, vb0, o20, 0, 0, 0);
            o21 = __builtin_amdgcn_mfma_f32_16x16x32_bf16(pa0, vb1, o21, 0, 0, 0);
            o20 = __builtin_amdgcn_mfma_f32_16x16x32_bf16(pa1, vb2, o20, 0, 0, 0);
            o21 = __builtin_amdgcn_mfma_f32_16x16x32_bf16(pa1, vb3, o21, 0, 0, 0);
        }
        // qi = 3
        {
            v4f s0 = __builtin_amdgcn_mfma_f32_16x16x32_bf16(ka0, qf3, zf, 0, 0, 0);
            v4f s1 = __builtin_amdgcn_mfma_f32_16x16x32_bf16(ka1, qf3, zf, 0, 0, 0);
            v4f s2 = __builtin_amdgcn_mfma_f32_16x16x32_bf16(ka2, qf3, zf, 0, 0, 0);
            v4f s3 = __builtin_amdgcn_mfma_f32_16x16x32_bf16(ka3, qf3, zf, 0, 0, 0);
            uint2 a0 = expack2(s0, l3), a1 = expack2(s1, l3);
            uint2 a2 = expack2(s2, l3), a3 = expack2(s3, l3);
            v8s pa0 = u4v8(a0, a1), pa1 = u4v8(a2, a3);
            o30 = __builtin_amdgcn_mfma_f32_16x16x32_bf16(pa0, vb0, o30, 0, 0, 0);
            o31 = __builtin_amdgcn_mfma_f32_16x16x32_bf16(pa0, vb1, o31, 0, 0, 0);
            o30 = __builtin_amdgcn_mfma_f32_16x16x32_bf16(pa1, vb2, o30, 0, 0, 0);
            o31 = __builtin_amdgcn_mfma_f32_16x16x32_bf16(pa1, vb3, o31, 0, 0, 0);
        }

        ka0 = nk0; ka1 = nk1; ka2 = nk2; ka3 = nk3;
        vb0 = nv0; vb1 = nv1; vb2 = nv2; vb3 = nv3;
    }

    float lf[4] = {l0, l1, l2, l3};
    v4f oq0[4] = {o00, o10, o20, o30};
    v4f oq1[4] = {o01, o11, o21, o31};
    #pragma unroll
    for (int qi = 0; qi < 4; qi++) {
        float lfq = lf[qi];
        lfq += __shfl_xor(lfq, 16);
        lfq += __shfl_xor(lfq, 32);
        float inv = 1.f / lfq;
        float invq[4];
        #pragma unroll
        for (int r = 0; r < 4; r++) invq[r] = __shfl(inv, g * 4 + r);
        #pragma unroll
        for (int r = 0; r < 4; r++) {
            size_t row = ((size_t)b * 4096 + qbase + qi * 16 + g * 4 + r) * 256 + h * 32;
            projT[row + m]      = f2bf(bf2f(gxT[row + m])      + oq0[qi][r] * invq[r]);
            projT[row + 16 + m] = f2bf(bf2f(gxT[row + 16 + m]) + oq1[qi][r] * invq[r]);
        }
    }
}

// ---------------- launcher ----------------
extern "C" void kernel_launch(void* const* d_in, const int* in_sizes, int n_in,
                              void* d_out, int out_size, void* d_ws, size_t ws_size,
                              hipStream_t stream)
{
    const float* x           = (const float*)d_in[0];
    const float* norm_w      = (const float*)d_in[1];
    const float* norm_b      = (const float*)d_in[2];
    const float* qkv_w       = (const float*)d_in[3];
    const float* qkv_b       = (const float*)d_in[4];
    const float* proj_w      = (const float*)d_in[5];
    const float* proj_b      = (const float*)d_in[6];
    const float* grid_norm_w = (const float*)d_in[7];
    const float* grid_norm_b = (const float*)d_in[8];
    const float* pm_ln_w     = (const float*)d_in[9];
    const float* pm_ln_b     = (const float*)d_in[10];
    const float* pm_red_w    = (const float*)d_in[11];
    const float* ds_norm_w   = (const float*)d_in[12];
    const float* ds_norm_b   = (const float*)d_in[13];
    const float* q_w         = (const float*)d_in[14];
    const float* q_b         = (const float*)d_in[15];
    const float* kv_w        = (const float*)d_in[16];
    const float* kv_b        = (const float*)d_in[17];
    float* out = (float*)d_out;

    float* wsf = (float*)d_ws;
    unsigned short* qkp   = (unsigned short*)(wsf);
    unsigned short* vbb   = (unsigned short*)(wsf + 4194304);
    unsigned short* mnb   = (unsigned short*)(wsf);
    unsigned short* kTu   = (unsigned short*)(wsf);
    unsigned short* vTu   = (unsigned short*)(wsf + 524288);
    float* pm             = wsf + 2097152;
    unsigned short* pmT   = (unsigned short*)(wsf + 3145728);
    unsigned short* qTu   = (unsigned short*)(wsf + 10485760);
    unsigned short* gxb   = (unsigned short*)(wsf + 12582912);
    unsigned short* projT = (unsigned short*)(wsf + 12582912);  // gxb dead before step 11
    unsigned short* xT    = (unsigned short*)(wsf + 16777216);
    unsigned short* gxT   = (unsigned short*)(wsf + 16777216);
    float* part   = wsf + 18874368;
    unsigned short* wbf   = (unsigned short*)(wsf + 18875392);
    unsigned short* wbf_qkv  = wbf;
    unsigned short* wbf_pm   = wbf + 196608;
    unsigned short* wbf_kv   = wbf + 458752;
    unsigned short* wbf_q    = wbf + 589824;
    unsigned short* wbf_proj = wbf + 655360;

    // 1. weights -> bf16  +  partial stats of x (fused, independent block ranges)
    prep_kernel<<<960, 256, 0, stream>>>(qkv_w, pm_red_w, kv_w, q_w, proj_w, wbf, x, part);
    // 2. xT = bf16(GN(x)) p-major (stats finalized inline)
    tnc<<<dim3(64, 4, BATCH), 256, 0, stream>>>(
        x, nullptr, part, 64, 1.f / 1048576.f, EPS_GN, norm_w, norm_b, xT, 4096);
    // 3. qkv GEMM (MFMA 128x128) -> qkp + vbb
    gemm_bf16<1><<<dim3(32, 6, BATCH), 256, 0, stream>>>(
        xT, wbf_qkv, qkv_b, nullptr, qkp, vbb, nullptr, 256, 4096, 768, 1.f);
    // 4. local windowed attention (MFMA, LDS-free) -> gxb bf16 c-major
    local_attn_mfma<<<2048, 256, 0, stream>>>(qkp, vbb, gxb);
    // 5. partial stats of x+gx
    gn_partial4<<<BATCH * 64, 256, 0, stream>>>(x, gxb, 262144, 64, part);
    // 6. gxT = bf16(GN(x+gx)) p-major
    tnc<<<dim3(64, 4, BATCH), 256, 0, stream>>>(
        x, gxb, part, 64, 1.f / 1048576.f, EPS_GN, grid_norm_w, grid_norm_b, gxT, 4096);
    // 7. FUSED: q GEMM (blocks 0..255) + patch-merge LN (blocks 256..4351)
    pmln_qgemm<<<4352, 256, 0, stream>>>(
        gxT, wbf_q, q_b, qTu, pm_ln_w, pm_ln_b, mnb, SCL2);
    // 8. patch-merge reduction GEMM (MFMA 128x128) + fused GN stage-1 partials
    gemm_bf16<0><<<dim3(8, 2, BATCH), 256, 0, stream>>>(
        mnb, wbf_pm, nullptr, pm, nullptr, nullptr, part, 1024, 1024, 256, 1.f);
    // 9. pmT = bf16(GN(pm)) p-major (nblk = 16 tiles/batch from step 8)
    tnc<<<dim3(16, 4, BATCH), 256, 0, stream>>>(
        pm, nullptr, part, 16, 1.f / 262144.f, EPS_GN, ds_norm_w, ds_norm_b, pmT, 1024);
    // 10. kv GEMM (MFMA 128x128) -> kTu (p-major) + vTu (c-major, vperm'd)
    gemm_bf16<3><<<dim3(8, 4, BATCH), 256, 0, stream>>>(
        pmT, wbf_kv, kv_b, nullptr, kTu, vTu, nullptr, 256, 1024, 512, 1.f);
    // 11. global attention (MFMA, 4 Q-frags/wave, pinned prefetch) -> projT = bf16(gxT + O)
    global_attn_mfma<<<512, 256, 0, stream>>>(qTu, kTu, vTu, gxT, projT);
    // 12. proj GEMM (MFMA 128x128) -> out
    gemm_bf16<0><<<dim3(32, 2, BATCH), 256, 0, stream>>>(
        projT, wbf_proj, proj_b, out, nullptr, nullptr, nullptr, 256, 4096, 256, 1.f);
}